// Round 13
// baseline (695.414 us; speedup 1.0000x reference)
//
#include <hip/hip_runtime.h>
#include <hip/hip_bf16.h>
#include <stdint.h>

typedef __bf16 bf16;
typedef __bf16 bf16x8 __attribute__((ext_vector_type(8)));
typedef __bf16 bf16x4 __attribute__((ext_vector_type(4)));
typedef float f32x4 __attribute__((ext_vector_type(4)));

static constexpr int BATCH = 4;
static constexpr int CH    = 512;
static constexpr int HH    = 64;
static constexpr int WW    = 80;
static constexpr int NSPAT = HH * WW;       // 5120
static constexpr int KCH   = 256;
static constexpr int VCH   = 512;
static constexpr int HPAD  = HH + 2;        // 66
static constexpr int WPAD  = WW + 2;        // 82
static constexpr int NPAD  = HPAD * WPAD;   // 5412
static constexpr float BN_EPS = 1e-5f;

enum { MODE_LIN = 0, MODE_PAD = 1, MODE_CONV = 2, MODE_SIMF32 = 3 };
enum { EPI_KF = 0, EPI_SBF = 1, EPI_SF32 = 2, EPI_V1 = 3, EPI_V = 4, EPI_CTX = 5 };

__device__ __forceinline__ void gll16(const void* g, void* l) {
  __builtin_amdgcn_global_load_lds((const __attribute__((address_space(1))) void*)g,
                                   (__attribute__((address_space(3))) void*)l,
                                   16, 0, 0);
}

// ---------------------------------------------------------------------------
// k_gemm2 (R7-verified): deep-pipelined GEMM, BM=256. Used for G1, G2.
template<int MODE, int EPI, int KDIM, int REMAP>
__global__ __launch_bounds__(512, 4)
void k_gemm2(const bf16* __restrict__ Ag, const void* __restrict__ Bg,
             void* __restrict__ Og, const float* __restrict__ ep0,
             const float* __restrict__ ep1,
             long Astr, long Bstr, long Ostr, int ntn) {
  __shared__ bf16 As[3 * 8192];   // ring-3 of 256x32
  __shared__ bf16 Bs[4 * 4096];   // ring-4 of 128x32
  constexpr int NT = KDIM / 32;
  static_assert(NT >= 4, "pipeline needs >=4 K-tiles");
  const int tid  = threadIdx.x;
  const int wave = tid >> 6;
  const int lane = tid & 63;
  const int b    = blockIdx.z;

  int m_t, n_t;
  if constexpr (REMAP == 1) {
    const int d = blockIdx.x;
    const int xl = d & 7, r = d >> 3;
    m_t = r & 1;
    n_t = (r >> 1) * 8 + xl;
  } else {
    m_t = blockIdx.x / ntn;
    n_t = blockIdx.x % ntn;
  }
  const int m0 = m_t * 256, n0 = n_t * 128;

  const int srow = tid >> 2;
  const int gq   = (tid & 3) ^ ((tid >> 3) & 3);
  const bf16* Ab = Ag + (long)b * Astr;
  const bf16* aS = Ab + (long)(m0 + srow) * KDIM + gq * 8;
  const bf16* BbB = (const bf16*)Bg + (long)b * Bstr;
  const bf16* bS = nullptr;
  int bsp = 0;
  if constexpr (MODE == MODE_LIN) {
    bS = BbB + (long)(n0 + srow) * KDIM + gq * 8;
  } else if constexpr (MODE == MODE_PAD) {
    const int nb = n0 + srow;
    bS = BbB + ((long)((nb / WW + 1) * WPAD + (nb % WW) + 1)) * CH + gq * 8;
  } else { // MODE_CONV
    const int nb = n0 + srow;
    bsp = (nb / WW) * WPAD + (nb % WW);
  }

  auto STAGE_A = [&](int k0, int buf, int s) {
    gll16(aS + (long)s * (128 * KDIM) + k0, As + buf * 8192 + s * 4096 + tid * 8);
  };
  auto STAGE_B = [&](int k0, int buf) {
    if constexpr (MODE == MODE_LIN || MODE == MODE_PAD) {
      gll16(bS + k0, Bs + buf * 4096 + tid * 8);
    } else {
      const int tap = k0 >> 9, within = k0 & 511;
      const int kh = tap / 3, kw = tap - kh * 3;
      const int off = kh * WPAD + kw;
      gll16(BbB + (long)(bsp + off) * CH + within + gq * 8, Bs + buf * 4096 + tid * 8);
    }
  };

  const int fr = lane & 15, q0 = lane >> 4;
  const int wm = wave >> 2, wn = wave & 3;
  const int ksw  = ((q0 ^ ((fr >> 1) & 3))) * 8;
  const int aoff = (wm * 128 + fr) * 32 + ksw;
  const int boff = (wn * 32 + fr) * 32 + ksw;

  f32x4 acc[8][2] = {};

  STAGE_A(0, 0, 0); STAGE_A(0, 0, 1); STAGE_B(0, 0);
  STAGE_A(32, 1, 0); STAGE_A(32, 1, 1); STAGE_B(32, 1);
  if (2 < NT) STAGE_B(64, 2);
  asm volatile("s_waitcnt vmcnt(4)" ::: "memory");
  __builtin_amdgcn_sched_barrier(0);
  __builtin_amdgcn_s_barrier();
  __builtin_amdgcn_sched_barrier(0);

  int ca = 0;
  for (int t = 0; t < NT; ++t) {
    const int cb = t & 3;
    const bf16* Ac = As + ca * 8192 + aoff;
    const bf16* Bc = Bs + cb * 4096 + boff;
    const int na = ca + 2 >= 3 ? ca - 1 : ca + 2;
    const int nb = (t + 3) & 3;

    bf16x8 a0[4], bf_[2];
    #pragma unroll
    for (int i = 0; i < 4; ++i) a0[i] = *(const bf16x8*)(Ac + i * 512);
    #pragma unroll
    for (int j = 0; j < 2; ++j) bf_[j] = *(const bf16x8*)(Bc + j * 512);
    if (t + 2 < NT) { STAGE_A((t + 2) * 32, na, 0); STAGE_A((t + 2) * 32, na, 1); }
    __builtin_amdgcn_s_setprio(1);
    #pragma unroll
    for (int i = 0; i < 4; ++i)
      #pragma unroll
      for (int j = 0; j < 2; ++j)
        acc[i][j] = __builtin_amdgcn_mfma_f32_16x16x32_bf16(a0[i], bf_[j], acc[i][j], 0, 0, 0);
    __builtin_amdgcn_s_setprio(0);

    bf16x8 a1[4];
    #pragma unroll
    for (int i = 0; i < 4; ++i) a1[i] = *(const bf16x8*)(Ac + (i + 4) * 512);
    if (t + 3 < NT) STAGE_B((t + 3) * 32, nb);
    __builtin_amdgcn_s_setprio(1);
    #pragma unroll
    for (int i = 0; i < 4; ++i)
      #pragma unroll
      for (int j = 0; j < 2; ++j)
        acc[i + 4][j] = __builtin_amdgcn_mfma_f32_16x16x32_bf16(a1[i], bf_[j], acc[i + 4][j], 0, 0, 0);
    __builtin_amdgcn_s_setprio(0);

    if (t + 1 < NT) {
      if (t + 3 < NT)      { asm volatile("s_waitcnt vmcnt(4)" ::: "memory"); }
      else if (t + 2 < NT) { asm volatile("s_waitcnt vmcnt(3)" ::: "memory"); }
      else                 { asm volatile("s_waitcnt vmcnt(0)" ::: "memory"); }
      __builtin_amdgcn_sched_barrier(0);
      __builtin_amdgcn_s_barrier();
      __builtin_amdgcn_sched_barrier(0);
    }
    ca = (ca + 1 >= 3) ? 0 : ca + 1;
  }

  const int row0 = m0 + wm * 128 + q0 * 4;
  const int col0 = n0 + wn * 32 + fr;
  const long zo  = (long)b * Ostr;

  if constexpr (EPI == EPI_KF) {
    bf16* op = (bf16*)Og + zo;
    #pragma unroll
    for (int i = 0; i < 8; ++i) {
      const int m = row0 + i * 16;
      float sc[4], bi[4];
      #pragma unroll
      for (int r = 0; r < 4; ++r) { sc[r] = ep0[m + r]; bi[r] = ep1[m + r]; }
      #pragma unroll
      for (int j = 0; j < 2; ++j) {
        bf16x4 pk;
        #pragma unroll
        for (int r = 0; r < 4; ++r)
          pk[r] = (bf16)fmaxf(acc[i][j][r] * sc[r] + bi[r], 0.0f);
        *(bf16x4*)(op + (long)(col0 + j * 16) * KCH + m) = pk;
      }
    }
  } else if constexpr (EPI == EPI_SBF) {
    bf16* op = (bf16*)Og + zo;   // transposed [n][m] (S symmetric)
    #pragma unroll
    for (int i = 0; i < 8; ++i)
      #pragma unroll
      for (int j = 0; j < 2; ++j) {
        bf16x4 pk;
        #pragma unroll
        for (int r = 0; r < 4; ++r) pk[r] = (bf16)(acc[i][j][r] * 0.0625f);
        *(bf16x4*)(op + (long)(col0 + j * 16) * NSPAT + row0 + i * 16) = pk;
      }
  } else if constexpr (EPI == EPI_V1) {
    bf16* op = (bf16*)Og + zo;
    #pragma unroll
    for (int i = 0; i < 8; ++i) {
      const int m = row0 + i * 16;
      #pragma unroll
      for (int j = 0; j < 2; ++j) {
        bf16x4 pk;
        #pragma unroll
        for (int r = 0; r < 4; ++r)
          pk[r] = (bf16)fmaxf(acc[i][j][r] + ep0[m + r], 0.0f);
        *(bf16x4*)(op + (long)(col0 + j * 16) * VCH + m) = pk;
      }
    }
  } else if constexpr (EPI == EPI_V) {
    bf16* op = (bf16*)Og + zo;
    #pragma unroll
    for (int i = 0; i < 8; ++i)
      #pragma unroll
      for (int r = 0; r < 4; ++r) {
        const int m = row0 + i * 16 + r;
        const float bi = ep0[m];
        #pragma unroll
        for (int j = 0; j < 2; ++j)
          op[(long)m * NSPAT + col0 + j * 16] = (bf16)fmaxf(acc[i][j][r] + bi, 0.0f);
      }
  } else { // EPI_CTX
    float* op = (float*)Og + zo;
    #pragma unroll
    for (int i = 0; i < 8; ++i)
      #pragma unroll
      for (int r = 0; r < 4; ++r) {
        const long base = (long)(row0 + i * 16 + r) * NSPAT;
        #pragma unroll
        for (int j = 0; j < 2; ++j)
          op[base + col0 + j * 16] = acc[i][j][r];
      }
  }
}

// ---------------------------------------------------------------------------
// k_gemm3: BM=128 grid-balanced variant of k_gemm2 (G3, G4, G5).
// BM=128 BN=128 BK=32, 512 thr (8 waves 2Mx4N), per-wave out 64x32.
// A ring-3 (24 KB) + B ring-4 (32 KB) = 56 KiB -> 2 blocks/CU. Grid 160/batch
// (4 m-tiles x 40 n-tiles) -> 640 blocks: makespan ~1.5 half-units vs 2.0.
// Per-iter issues 1 A + 1 B load -> same FIFO: boundary vmcnt(3)/(2)/(0).
// REMAP: 4 m-blocks of one n-tile land on one XCD (B-panel 1.3 MB < 4 MB L2).
template<int MODE, int EPI, int KDIM>
__global__ __launch_bounds__(512, 4)
void k_gemm3(const bf16* __restrict__ Ag, const void* __restrict__ Bg,
             void* __restrict__ Og, const float* __restrict__ ep0,
             long Astr, long Bstr, long Ostr) {
  __shared__ bf16 As[3 * 4096];   // ring-3 of 128x32
  __shared__ bf16 Bs[4 * 4096];   // ring-4 of 128x32
  constexpr int NT = KDIM / 32;
  static_assert(NT >= 4, "pipeline needs >=4 K-tiles");
  const int tid  = threadIdx.x;
  const int wave = tid >> 6;
  const int lane = tid & 63;
  const int b    = blockIdx.z;

  // d in [0,160): xl=XCD, r>>2 selects n-group, r&3 = m-tile. Bijective.
  const int d  = blockIdx.x;
  const int xl = d & 7, r = d >> 3;
  const int m_t = r & 3;
  const int n_t = (r >> 2) * 8 + xl;
  const int m0 = m_t * 128, n0 = n_t * 128;

  const int srow = tid >> 2;          // 128 rows
  const int gq   = (tid & 3) ^ ((tid >> 3) & 3);
  const bf16* aS = Ag + (long)b * Astr + (long)(m0 + srow) * KDIM + gq * 8;
  const bf16* BbB = (const bf16*)Bg + (long)b * Bstr;
  const bf16* bS = nullptr;
  int bsp = 0;
  if constexpr (MODE == MODE_LIN) {
    bS = BbB + (long)(n0 + srow) * KDIM + gq * 8;
  } else { // MODE_CONV
    const int nb = n0 + srow;
    bsp = (nb / WW) * WPAD + (nb % WW);
  }

  auto STAGE_A = [&](int k0, int buf) {
    gll16(aS + k0, As + buf * 4096 + tid * 8);
  };
  auto STAGE_B = [&](int k0, int buf) {
    if constexpr (MODE == MODE_LIN) {
      gll16(bS + k0, Bs + buf * 4096 + tid * 8);
    } else {
      const int tap = k0 >> 9, within = k0 & 511;
      const int kh = tap / 3, kw = tap - kh * 3;
      const int off = kh * WPAD + kw;
      gll16(BbB + (long)(bsp + off) * CH + within + gq * 8, Bs + buf * 4096 + tid * 8);
    }
  };

  const int fr = lane & 15, q0 = lane >> 4;
  const int wm = wave >> 2, wn = wave & 3;
  const int ksw  = ((q0 ^ ((fr >> 1) & 3))) * 8;
  const int aoff = (wm * 64 + fr) * 32 + ksw;
  const int boff = (wn * 32 + fr) * 32 + ksw;

  f32x4 acc[4][2] = {};

  // prologue: A0,B0,A1,B1,B2 (5 loads); keep newest 3 {A1,B1,B2}.
  STAGE_A(0, 0); STAGE_B(0, 0);
  STAGE_A(32, 1); STAGE_B(32, 1);
  if (2 < NT) STAGE_B(64, 2);
  asm volatile("s_waitcnt vmcnt(3)" ::: "memory");
  __builtin_amdgcn_sched_barrier(0);
  __builtin_amdgcn_s_barrier();
  __builtin_amdgcn_sched_barrier(0);

  int ca = 0;
  for (int t = 0; t < NT; ++t) {
    const int cb = t & 3;
    const bf16* Ac = As + ca * 4096 + aoff;
    const bf16* Bc = Bs + cb * 4096 + boff;
    const int na = ca + 2 >= 3 ? ca - 1 : ca + 2;
    const int nb = (t + 3) & 3;

    // phase 0: A rows 0..1 x both B cols; stage A(t+2)
    bf16x8 a0[2], bf_[2];
    #pragma unroll
    for (int i = 0; i < 2; ++i) a0[i] = *(const bf16x8*)(Ac + i * 512);
    #pragma unroll
    for (int j = 0; j < 2; ++j) bf_[j] = *(const bf16x8*)(Bc + j * 512);
    if (t + 2 < NT) STAGE_A((t + 2) * 32, na);
    __builtin_amdgcn_s_setprio(1);
    #pragma unroll
    for (int i = 0; i < 2; ++i)
      #pragma unroll
      for (int j = 0; j < 2; ++j)
        acc[i][j] = __builtin_amdgcn_mfma_f32_16x16x32_bf16(a0[i], bf_[j], acc[i][j], 0, 0, 0);
    __builtin_amdgcn_s_setprio(0);

    // phase 1: A rows 2..3; stage B(t+3)
    bf16x8 a1[2];
    #pragma unroll
    for (int i = 0; i < 2; ++i) a1[i] = *(const bf16x8*)(Ac + (i + 2) * 512);
    if (t + 3 < NT) STAGE_B((t + 3) * 32, nb);
    __builtin_amdgcn_s_setprio(1);
    #pragma unroll
    for (int i = 0; i < 2; ++i)
      #pragma unroll
      for (int j = 0; j < 2; ++j)
        acc[i + 2][j] = __builtin_amdgcn_mfma_f32_16x16x32_bf16(a1[i], bf_[j], acc[i + 2][j], 0, 0, 0);
    __builtin_amdgcn_s_setprio(0);

    if (t + 1 < NT) {
      if (t + 3 < NT)      { asm volatile("s_waitcnt vmcnt(3)" ::: "memory"); }
      else if (t + 2 < NT) { asm volatile("s_waitcnt vmcnt(2)" ::: "memory"); }
      else                 { asm volatile("s_waitcnt vmcnt(0)" ::: "memory"); }
      __builtin_amdgcn_sched_barrier(0);
      __builtin_amdgcn_s_barrier();
      __builtin_amdgcn_sched_barrier(0);
    }
    ca = (ca + 1 >= 3) ? 0 : ca + 1;
  }

  const int row0 = m0 + wm * 64 + q0 * 4;    // M (+i*16+r)
  const int col0 = n0 + wn * 32 + fr;        // N (+j*16)
  const long zo  = (long)b * Ostr;

  if constexpr (EPI == EPI_V1) {
    bf16* op = (bf16*)Og + zo;   // v1T [n][vc]
    #pragma unroll
    for (int i = 0; i < 4; ++i) {
      const int m = row0 + i * 16;
      #pragma unroll
      for (int j = 0; j < 2; ++j) {
        bf16x4 pk;
        #pragma unroll
        for (int r = 0; r < 4; ++r)
          pk[r] = (bf16)fmaxf(acc[i][j][r] + ep0[m + r], 0.0f);
        *(bf16x4*)(op + (long)(col0 + j * 16) * VCH + m) = pk;
      }
    }
  } else if constexpr (EPI == EPI_V) {
    bf16* op = (bf16*)Og + zo;   // v[m][n] row-major
    #pragma unroll
    for (int i = 0; i < 4; ++i)
      #pragma unroll
      for (int r = 0; r < 4; ++r) {
        const int m = row0 + i * 16 + r;
        const float bi = ep0[m];
        #pragma unroll
        for (int j = 0; j < 2; ++j)
          op[(long)m * NSPAT + col0 + j * 16] = (bf16)fmaxf(acc[i][j][r] + bi, 0.0f);
      }
  } else { // EPI_CTX: f32 [m][n]
    float* op = (float*)Og + zo;
    #pragma unroll
    for (int i = 0; i < 4; ++i)
      #pragma unroll
      for (int r = 0; r < 4; ++r) {
        const long base = (long)(row0 + i * 16 + r) * NSPAT;
        #pragma unroll
        for (int j = 0; j < 2; ++j)
          op[base + col0 + j * 16] = acc[i][j][r];
      }
  }
}

// ---------------------------------------------------------------------------
// legacy 128x128 kernel (fallback paths only)
template<int MODE, int EPI, int KDIM, int NY>
__global__ __launch_bounds__(256)
void k_gemm(const bf16* __restrict__ Ag, const void* __restrict__ Bg,
            void* __restrict__ Og, const float* __restrict__ ep0,
            const float* __restrict__ ep1,
            long Astr, long Bstr, long Ostr) {
  __shared__ bf16 As[2 * 128 * 32];
  __shared__ bf16 Bs[2 * 128 * 32];
  const int tid  = threadIdx.x;
  const int wave = tid >> 6;
  const int lane = tid & 63;
  const int b    = blockIdx.z;

  const int d  = blockIdx.x;
  const int xl = d & 7;
  const int y  = (d >> 3) % NY;
  const int xh = d / (8 * NY);
  const int n0 = (xh * 8 + xl) * 128;
  const int m0 = y * 128;

  const int rloc = lane >> 2;
  const int cswz = (lane & 3) ^ ((lane >> 3) & 3);
  const int colo = cswz * 8;
  const int r0   = wave * 32 + rloc;
  const int r1   = r0 + 16;

  const bf16* Ab  = Ag + (long)b * Astr;
  const bf16* ag0 = Ab + (long)(m0 + r0) * KDIM + colo;
  const bf16* ag1 = Ab + (long)(m0 + r1) * KDIM + colo;
  bf16* al0 = As + wave * 1024;
  bf16* al1 = As + wave * 1024 + 512;
  bf16* bl0 = Bs + wave * 1024;
  bf16* bl1 = Bs + wave * 1024 + 512;

  const bf16*  BbB = (const bf16*)Bg + (long)b * Bstr;
  const float* Sg  = (const float*)Bg + (long)b * Bstr;
  const bf16* bg0 = nullptr;
  const bf16* bg1 = nullptr;
  if constexpr (MODE == MODE_LIN) {
    bg0 = BbB + (long)(n0 + r0) * KDIM + colo;
    bg1 = BbB + (long)(n0 + r1) * KDIM + colo;
  } else if constexpr (MODE == MODE_PAD) {
    const int na = n0 + r0, nb = n0 + r1;
    bg0 = BbB + ((long)((na / WW + 1) * WPAD + (na % WW) + 1)) * CH + colo;
    bg1 = BbB + ((long)((nb / WW + 1) * WPAD + (nb % WW) + 1)) * CH + colo;
  }

  auto STAGE = [&](int k0, int buf) {
    const int o = buf << 12;
    gll16(ag0 + k0, al0 + o);
    gll16(ag1 + k0, al1 + o);
    if constexpr (MODE == MODE_LIN || MODE == MODE_PAD) {
      gll16(bg0 + k0, bl0 + o);
      gll16(bg1 + k0, bl1 + o);
    } else { // MODE_SIMF32
      #pragma unroll
      for (int p = 0; p < 4; ++p) {
        const int idx = p * 256 + tid;
        const int rr  = idx >> 3;
        const int cg  = (idx & 7) * 4;
        const float4 f = *(const float4*)(Sg + (long)(n0 + rr) * NSPAT + k0 + cg);
        bf16x4 hq;
        hq[0] = (bf16)f.x; hq[1] = (bf16)f.y; hq[2] = (bf16)f.z; hq[3] = (bf16)f.w;
        const int chunk = cg >> 3;
        const int swc   = (((chunk ^ ((rr >> 1) & 3)) << 3) | (cg & 7));
        *(bf16x4*)(Bs + o + rr * 32 + swc) = hq;
      }
    }
  };

  f32x4 acc[4][4] = {};

  const int wm = wave >> 1, wn = wave & 1;
  const int fr  = lane & 15;
  const int qsw = (((lane >> 4) ^ ((fr >> 1) & 3)) << 3);
  const bf16* ArF = As + (wm * 64 + fr) * 32 + qsw;
  const bf16* BrF = Bs + (wn * 64 + fr) * 32 + qsw;

  STAGE(0, 0);
  __syncthreads();
  int cur = 0;
  for (int k0 = 0; k0 < KDIM; k0 += 32) {
    if (k0 + 32 < KDIM) STAGE(k0 + 32, cur ^ 1);
    const int off = cur << 12;
    bf16x8 af[4], bfv[4];
    #pragma unroll
    for (int i = 0; i < 4; ++i) af[i] = *(const bf16x8*)(ArF + off + i * 512);
    #pragma unroll
    for (int j = 0; j < 4; ++j) bfv[j] = *(const bf16x8*)(BrF + off + j * 512);
    #pragma unroll
    for (int i = 0; i < 4; ++i)
      #pragma unroll
      for (int j = 0; j < 4; ++j)
        acc[i][j] = __builtin_amdgcn_mfma_f32_16x16x32_bf16(af[i], bfv[j], acc[i][j], 0, 0, 0);
    __syncthreads();
    cur ^= 1;
  }

  const int row0 = m0 + wm * 64 + (lane >> 4) * 4;
  const int col0 = n0 + wn * 64 + (lane & 15);
  const long zo  = (long)b * Ostr;

  if constexpr (EPI == EPI_KF) {
    bf16* op = (bf16*)Og + zo;
    #pragma unroll
    for (int i = 0; i < 4; ++i) {
      const int m = row0 + i * 16;
      float sc[4], bi[4];
      #pragma unroll
      for (int r = 0; r < 4; ++r) { sc[r] = ep0[m + r]; bi[r] = ep1[m + r]; }
      #pragma unroll
      for (int j = 0; j < 4; ++j) {
        const int n = col0 + j * 16;
        bf16x4 pk;
        #pragma unroll
        for (int r = 0; r < 4; ++r)
          pk[r] = (bf16)fmaxf(acc[i][j][r] * sc[r] + bi[r], 0.0f);
        *(bf16x4*)(op + (long)n * KCH + m) = pk;
      }
    }
  } else if constexpr (EPI == EPI_SF32) {
    float* op = (float*)Og + zo;
    #pragma unroll
    for (int i = 0; i < 4; ++i)
      #pragma unroll
      for (int j = 0; j < 4; ++j) {
        f32x4 sv = acc[i][j];
        sv[0] *= 0.0625f; sv[1] *= 0.0625f; sv[2] *= 0.0625f; sv[3] *= 0.0625f;
        *(f32x4*)(op + (long)(col0 + j * 16) * NSPAT + row0 + i * 16) = sv;
      }
  } else if constexpr (EPI == EPI_V) {
    bf16* op = (bf16*)Og + zo;   // v[m][n]
    #pragma unroll
    for (int i = 0; i < 4; ++i)
      #pragma unroll
      for (int r = 0; r < 4; ++r) {
        const int m = row0 + i * 16 + r;
        const float bi = ep0[m];
        #pragma unroll
        for (int j = 0; j < 4; ++j)
          op[(long)m * NSPAT + col0 + j * 16] = (bf16)fmaxf(acc[i][j][r] + bi, 0.0f);
      }
  } else { // EPI_CTX f32 [m][n]
    float* op = (float*)Og + zo;
    #pragma unroll
    for (int i = 0; i < 4; ++i)
      #pragma unroll
      for (int r = 0; r < 4; ++r) {
        const long base = (long)(row0 + i * 16 + r) * NSPAT;
        #pragma unroll
        for (int j = 0; j < 4; ++j)
          op[base + col0 + j * 16] = acc[i][j][r];
      }
  }
}

// x [B][C][H][W] f32 -> xpadT [B][NPAD][C] bf16, borders zeroed here.
__global__ __launch_bounds__(256)
void k_xpad(const float* __restrict__ x, bf16* __restrict__ xp) {
  __shared__ float t[64 * 81];
  const int cb  = blockIdx.x;
  const int hp  = blockIdx.y;
  const int b   = blockIdx.z;
  const int tid = threadIdx.x;
  const bool border = (hp == 0) || (hp == HPAD - 1);
  if (!border) {
    const float* xb = x + ((long)b * CH + cb * 64) * NSPAT + (hp - 1) * WW;
    for (int idx = tid; idx < 64 * 80; idx += 256) {
      const int cl = idx / 80;
      const int w  = idx - cl * 80;
      t[cl * 81 + w] = xb[(long)cl * NSPAT + w];
    }
    __syncthreads();
  }
  bf16* op = xp + ((long)b * NPAD + (long)hp * WPAD) * CH + cb * 64;
  for (int idx = tid; idx < WPAD * 64; idx += 256) {
    const int wp = idx >> 6;
    const int cl = idx & 63;
    float v = 0.0f;
    if (!border && wp >= 1 && wp <= WW) v = t[cl * 81 + (wp - 1)];
    op[(long)wp * CH + cl] = (bf16)v;
  }
}

__global__ void k_cvt(const float* __restrict__ in, bf16* __restrict__ out, int n) {
  const int i = blockIdx.x * 256 + threadIdx.x;
  if (i < n) out[i] = (bf16)in[i];
}

__global__ void k_cvt_wv1(const float* __restrict__ in, bf16* __restrict__ out) {
  const int o   = blockIdx.x * 256 + threadIdx.x;
  const int c   = o & 511;
  const int t2  = o >> 9;
  const int tap = t2 % 9;
  const int vc  = t2 / 9;
  out[o] = (bf16)in[((long)vc * 512 + c) * 9 + tap];
}

__global__ void k_bnp(const float* bk, const float* gamma, const float* beta,
                      const float* rmean, const float* rvar,
                      float* s, float* t) {
  const int k = threadIdx.x;
  const float sc = gamma[k] / sqrtf(rvar[k] + BN_EPS);
  s[k] = sc;
  t[k] = (bk[k] - rmean[k]) * sc + beta[k];
}

// read bf16 scores (16B loads), f32 softmax, write f32 sim (nontemporal, d_out)
// + bf16 sim in-place
__global__ __launch_bounds__(256)
void k_softmax_bf(bf16* __restrict__ Sb16, float* __restrict__ Sout) {
  const int tid = threadIdx.x;
  bf16*  p  = Sb16 + (long)blockIdx.x * NSPAT;
  float* po = Sout + (long)blockIdx.x * NSPAT;
  float v[20];
  float mx = -3.0e38f;
  {
    const bf16x8 h0 = *(const bf16x8*)(p + tid * 8);
    const bf16x8 h1 = *(const bf16x8*)(p + 2048 + tid * 8);
    const bf16x4 h2 = *(const bf16x4*)(p + 4096 + tid * 4);
    #pragma unroll
    for (int r = 0; r < 8; ++r) { v[r]     = (float)h0[r]; }
    #pragma unroll
    for (int r = 0; r < 8; ++r) { v[8 + r] = (float)h1[r]; }
    #pragma unroll
    for (int r = 0; r < 4; ++r) { v[16 + r] = (float)h2[r]; }
    #pragma unroll
    for (int e = 0; e < 20; ++e) mx = fmaxf(mx, v[e]);
  }
  __shared__ float red[4];
  #pragma unroll
  for (int o = 32; o > 0; o >>= 1) mx = fmaxf(mx, __shfl_xor(mx, o));
  if ((tid & 63) == 0) red[tid >> 6] = mx;
  __syncthreads();
  mx = fmaxf(fmaxf(red[0], red[1]), fmaxf(red[2], red[3]));
  float sum = 0.0f;
  #pragma unroll
  for (int e = 0; e < 20; ++e) { v[e] = __expf(v[e] - mx); sum += v[e]; }
  #pragma unroll
  for (int o = 32; o > 0; o >>= 1) sum += __shfl_xor(sum, o);
  __syncthreads();
  if ((tid & 63) == 0) red[tid >> 6] = sum;
  __syncthreads();
  sum = (red[0] + red[1]) + (red[2] + red[3]);
  const float inv = 1.0f / sum;
  #pragma unroll
  for (int e = 0; e < 20; ++e) v[e] *= inv;
  #pragma unroll
  for (int g = 0; g < 2; ++g) {
    #pragma unroll
    for (int h = 0; h < 2; ++h) {
      f32x4 o4;
      o4[0] = v[g * 8 + h * 4 + 0]; o4[1] = v[g * 8 + h * 4 + 1];
      o4[2] = v[g * 8 + h * 4 + 2]; o4[3] = v[g * 8 + h * 4 + 3];
      __builtin_nontemporal_store(o4, (f32x4*)(po + g * 2048 + tid * 8 + h * 4));
    }
  }
  {
    f32x4 o4;
    o4[0] = v[16]; o4[1] = v[17]; o4[2] = v[18]; o4[3] = v[19];
    __builtin_nontemporal_store(o4, (f32x4*)(po + 4096 + tid * 4));
  }
  {
    bf16x8 h0, h1;
    bf16x4 h2;
    #pragma unroll
    for (int r = 0; r < 8; ++r) { h0[r] = (bf16)v[r]; h1[r] = (bf16)v[8 + r]; }
    #pragma unroll
    for (int r = 0; r < 4; ++r) h2[r] = (bf16)v[16 + r];
    *(bf16x8*)(p + tid * 8) = h0;
    *(bf16x8*)(p + 2048 + tid * 8) = h1;
    *(bf16x4*)(p + 4096 + tid * 4) = h2;
  }
}

// fallback: f32 softmax in place
__global__ __launch_bounds__(256)
void k_softmax(float* __restrict__ S) {
  const int tid = threadIdx.x;
  float* p = S + (long)blockIdx.x * NSPAT;
  float4 v[5];
  float mx = -3.0e38f;
  #pragma unroll
  for (int q = 0; q < 5; ++q) {
    v[q] = *(const float4*)(p + (q * 256 + tid) * 4);
    mx = fmaxf(mx, fmaxf(fmaxf(v[q].x, v[q].y), fmaxf(v[q].z, v[q].w)));
  }
  __shared__ float red[4];
  #pragma unroll
  for (int o = 32; o > 0; o >>= 1) mx = fmaxf(mx, __shfl_xor(mx, o));
  if ((tid & 63) == 0) red[tid >> 6] = mx;
  __syncthreads();
  mx = fmaxf(fmaxf(red[0], red[1]), fmaxf(red[2], red[3]));
  float sum = 0.0f;
  #pragma unroll
  for (int q = 0; q < 5; ++q) {
    v[q].x = __expf(v[q].x - mx);
    v[q].y = __expf(v[q].y - mx);
    v[q].z = __expf(v[q].z - mx);
    v[q].w = __expf(v[q].w - mx);
    sum += (v[q].x + v[q].y) + (v[q].z + v[q].w);
  }
  #pragma unroll
  for (int o = 32; o > 0; o >>= 1) sum += __shfl_xor(sum, o);
  __syncthreads();
  if ((tid & 63) == 0) red[tid >> 6] = sum;
  __syncthreads();
  sum = (red[0] + red[1]) + (red[2] + red[3]);
  const float inv = 1.0f / sum;
  #pragma unroll
  for (int q = 0; q < 5; ++q) {
    float4 o4;
    o4.x = v[q].x * inv; o4.y = v[q].y * inv;
    o4.z = v[q].z * inv; o4.w = v[q].w * inv;
    *(float4*)(p + (q * 256 + tid) * 4) = o4;
  }
}

extern "C" void kernel_launch(void* const* d_in, const int* in_sizes, int n_in,
                              void* d_out, int out_size, void* d_ws, size_t ws_size,
                              hipStream_t stream) {
  const float* x     = (const float*)d_in[0];
  const float* wk    = (const float*)d_in[1];
  const float* bk    = (const float*)d_in[2];
  const float* gamma = (const float*)d_in[3];
  const float* beta  = (const float*)d_in[4];
  const float* rmean = (const float*)d_in[5];
  const float* rvar  = (const float*)d_in[6];
  const float* wv1   = (const float*)d_in[7];
  const float* bv1   = (const float*)d_in[8];
  const float* wv2   = (const float*)d_in[9];
  const float* bv2   = (const float*)d_in[10];

  float* ctx = (float*)d_out;                    // [B][VC][N]
  float* Sb  = ctx + (long)BATCH * VCH * NSPAT;  // [B][N][N] f32 sim output

  char* w = (char*)d_ws;
  auto alloc = [&](size_t bytes) {
    char* r = w;
    w += (bytes + 255) & ~(size_t)255;
    return r;
  };
  bf16*  xpadT = (bf16*)alloc((size_t)BATCH * NPAD * CH * 2);
  bf16*  kfT   = (bf16*)alloc((size_t)BATCH * NSPAT * KCH * 2);
  bf16*  v1T   = (bf16*)alloc((size_t)BATCH * NSPAT * VCH * 2);
  bf16*  vB    = (bf16*)alloc((size_t)BATCH * VCH * NSPAT * 2);
  bf16*  wkb   = (bf16*)alloc((size_t)KCH * CH * 2);
  bf16*  wv1b  = (bf16*)alloc((size_t)VCH * CH * 9 * 2);
  bf16*  wv2b  = (bf16*)alloc((size_t)VCH * VCH * 2);
  float* bnS   = (float*)alloc(KCH * 4);
  float* bnT   = (float*)alloc(KCH * 4);
  const size_t used = (size_t)(w - (char*)d_ws);
  if (ws_size < used) return;
  const size_t simbytes = (size_t)BATCH * NSPAT * NSPAT * 2;  // 209.7 MB
  bf16* simb = (ws_size - used >= simbytes) ? (bf16*)alloc(simbytes) : nullptr;

  k_xpad<<<dim3(8, HPAD, BATCH), 256, 0, stream>>>(x, xpadT);
  k_cvt<<<(KCH * CH) / 256, 256, 0, stream>>>(wk, wkb, KCH * CH);
  k_cvt_wv1<<<(VCH * CH * 9) / 256, 256, 0, stream>>>(wv1, wv1b);
  k_cvt<<<(VCH * VCH) / 256, 256, 0, stream>>>(wv2, wv2b, VCH * VCH);
  k_bnp<<<1, KCH, 0, stream>>>(bk, gamma, beta, rmean, rvar, bnS, bnT);

  // G1: kfT[b][n][kc] = relu(bn(wk . x))  (deep 256x128, one m-tile)
  k_gemm2<MODE_PAD, EPI_KF, CH, 0><<<dim3(40, 1, BATCH), 512, 0, stream>>>(
      wkb, xpadT, kfT, bnS, bnT, 0, (long)NPAD * CH, (long)NSPAT * KCH, 40);
  // G3: v1T[b][n][vc] = relu(conv3x3(x))  (BM=128 balanced, 160 blocks/batch)
  k_gemm3<MODE_CONV, EPI_V1, CH * 9><<<dim3(160, 1, BATCH), 512, 0, stream>>>(
      wv1b, xpadT, v1T, bv1, 0, (long)NPAD * CH, (long)NSPAT * VCH);
  // G4: v[b][vc][n] = relu(wv2 . v1)  (BM=128 balanced)
  k_gemm3<MODE_LIN, EPI_V, VCH><<<dim3(160, 1, BATCH), 512, 0, stream>>>(
      wv2b, v1T, vB, bv2, 0, (long)NSPAT * VCH, (long)VCH * NSPAT);

  if (simb) {
    // G2: bf16 scores -> simb (transposed-symmetric write), 800 blocks/batch
    k_gemm2<MODE_LIN, EPI_SBF, KCH, 0><<<dim3(20 * 40, 1, BATCH), 512, 0, stream>>>(
        kfT, kfT, simb, nullptr, nullptr, (long)NSPAT * KCH, (long)NSPAT * KCH, (long)NSPAT * NSPAT, 40);
    k_softmax_bf<<<BATCH * NSPAT, 256, 0, stream>>>(simb, Sb);
    // G5: context = v . sim^T  (BM=128 balanced, B-panel L2-resident per XCD)
    k_gemm3<MODE_LIN, EPI_CTX, NSPAT><<<dim3(160, 1, BATCH), 512, 0, stream>>>(
        vB, simb, ctx, nullptr, (long)VCH * NSPAT, (long)NSPAT * NSPAT, (long)VCH * NSPAT);
  } else {
    // fallback: f32 scores -> d_out sim region, in-place softmax, f32-staged G5
    k_gemm<MODE_LIN, EPI_SF32, KCH, 40><<<dim3(40 * 40, 1, BATCH), 256, 0, stream>>>(
        kfT, kfT, Sb, nullptr, nullptr, (long)NSPAT * KCH, (long)NSPAT * KCH, (long)NSPAT * NSPAT);
    k_softmax<<<BATCH * NSPAT, 256, 0, stream>>>(Sb);
    k_gemm<MODE_SIMF32, EPI_CTX, NSPAT, 4><<<dim3(40 * 4, 1, BATCH), 256, 0, stream>>>(
        vB, Sb, ctx, nullptr, nullptr, (long)VCH * NSPAT, (long)NSPAT * NSPAT, (long)VCH * NSPAT);
  }
}

// Round 14
// 611.319 us; speedup vs baseline: 1.1376x; 1.1376x over previous
//
#include <hip/hip_runtime.h>
#include <hip/hip_bf16.h>
#include <stdint.h>

typedef __bf16 bf16;
typedef __bf16 bf16x8 __attribute__((ext_vector_type(8)));
typedef __bf16 bf16x4 __attribute__((ext_vector_type(4)));
typedef float f32x4 __attribute__((ext_vector_type(4)));

static constexpr int BATCH = 4;
static constexpr int CH    = 512;
static constexpr int HH    = 64;
static constexpr int WW    = 80;
static constexpr int NSPAT = HH * WW;       // 5120
static constexpr int KCH   = 256;
static constexpr int VCH   = 512;
static constexpr int HPAD  = HH + 2;        // 66
static constexpr int WPAD  = WW + 2;        // 82
static constexpr int NPAD  = HPAD * WPAD;   // 5412
static constexpr float BN_EPS = 1e-5f;

enum { MODE_LIN = 0, MODE_PAD = 1, MODE_CONV = 2, MODE_SIMF32 = 3 };
enum { EPI_KF = 0, EPI_SBF = 1, EPI_SF32 = 2, EPI_V1 = 3, EPI_V = 4, EPI_CTX = 5 };

__device__ __forceinline__ void gll16(const void* g, void* l) {
  __builtin_amdgcn_global_load_lds((const __attribute__((address_space(1))) void*)g,
                                   (__attribute__((address_space(3))) void*)l,
                                   16, 0, 0);
}

// ---------------------------------------------------------------------------
// k_gemm2 (R7-verified): deep-pipelined GEMM, asymmetric ring depth.
// C[M,N] = A[M,K]*B[N,K]^T, bf16 in, f32 acc. BM=256, BN=128, BK=32,
// 512 threads (8 waves 2Mx4N), per-wave out 128x32.
// LDS: A ring-3 (3x16KB) + B ring-4 (4x8KB) = 80 KiB -> 2 blocks/CU.
// Schedule (iteration t): ph0 reads frags + stages A(t+2); MFMA x8;
//   ph1 reads a1 + stages B(t+3); MFMA x8; boundary wait + s_barrier.
// Issue-age order at boundary t: B(t+1),A(t+1)a,b | B(t+2) | A(t+2)a,b,B(t+3)
//   -> steady-state s_waitcnt vmcnt(4) completes exactly {B,A,A}(t+1);
//   B gets 2+ iterations of latency slack (HBM-cold sim stream in G5).
// Tail: vmcnt(3) when B(t+3) unstaged, vmcnt(0) when A(t+2) unstaged.
// T2 swizzle via pre-swizzled global source + swizzled ds_read.
template<int MODE, int EPI, int KDIM, int REMAP>
__global__ __launch_bounds__(512, 4)
void k_gemm2(const bf16* __restrict__ Ag, const void* __restrict__ Bg,
             void* __restrict__ Og, const float* __restrict__ ep0,
             const float* __restrict__ ep1,
             long Astr, long Bstr, long Ostr, int ntn) {
  __shared__ bf16 As[3 * 8192];   // ring-3 of 256x32
  __shared__ bf16 Bs[4 * 4096];   // ring-4 of 128x32
  constexpr int NT = KDIM / 32;
  static_assert(NT >= 4, "pipeline needs >=4 K-tiles");
  const int tid  = threadIdx.x;
  const int wave = tid >> 6;
  const int lane = tid & 63;
  const int b    = blockIdx.z;

  int m_t, n_t;
  if constexpr (REMAP == 1) {
    // 80 blocks/batch: pair (m0,m1) of one n-tile share an XCD (B-panel L2).
    const int d = blockIdx.x;
    const int xl = d & 7, r = d >> 3;
    m_t = r & 1;
    n_t = (r >> 1) * 8 + xl;
  } else {
    m_t = blockIdx.x / ntn;
    n_t = blockIdx.x % ntn;
  }
  const int m0 = m_t * 256, n0 = n_t * 128;

  const int srow = tid >> 2;
  const int gq   = (tid & 3) ^ ((tid >> 3) & 3);
  const bf16* Ab = Ag + (long)b * Astr;
  const bf16* aS = Ab + (long)(m0 + srow) * KDIM + gq * 8;
  const bf16* BbB = (const bf16*)Bg + (long)b * Bstr;
  const bf16* bS = nullptr;
  int bsp = 0;
  if constexpr (MODE == MODE_LIN) {
    bS = BbB + (long)(n0 + srow) * KDIM + gq * 8;
  } else if constexpr (MODE == MODE_PAD) {
    const int nb = n0 + srow;
    bS = BbB + ((long)((nb / WW + 1) * WPAD + (nb % WW) + 1)) * CH + gq * 8;
  } else { // MODE_CONV
    const int nb = n0 + srow;
    bsp = (nb / WW) * WPAD + (nb % WW);
  }

  auto STAGE_A = [&](int k0, int buf, int s) {
    gll16(aS + (long)s * (128 * KDIM) + k0, As + buf * 8192 + s * 4096 + tid * 8);
  };
  auto STAGE_B = [&](int k0, int buf) {
    if constexpr (MODE == MODE_LIN || MODE == MODE_PAD) {
      gll16(bS + k0, Bs + buf * 4096 + tid * 8);
    } else {
      const int tap = k0 >> 9, within = k0 & 511;
      const int kh = tap / 3, kw = tap - kh * 3;
      const int off = kh * WPAD + kw;
      gll16(BbB + (long)(bsp + off) * CH + within + gq * 8, Bs + buf * 4096 + tid * 8);
    }
  };

  const int fr = lane & 15, q0 = lane >> 4;
  const int wm = wave >> 2, wn = wave & 3;
  const int ksw  = ((q0 ^ ((fr >> 1) & 3))) * 8;
  const int aoff = (wm * 128 + fr) * 32 + ksw;
  const int boff = (wn * 32 + fr) * 32 + ksw;

  f32x4 acc[8][2] = {};

  // prologue: A(0),A(1); B(0),B(1),B(2). wait keeps {A1a,A1b,B1,B2}.
  STAGE_A(0, 0, 0); STAGE_A(0, 0, 1); STAGE_B(0, 0);
  STAGE_A(32, 1, 0); STAGE_A(32, 1, 1); STAGE_B(32, 1);
  if (2 < NT) STAGE_B(64, 2);
  asm volatile("s_waitcnt vmcnt(4)" ::: "memory");
  __builtin_amdgcn_sched_barrier(0);
  __builtin_amdgcn_s_barrier();
  __builtin_amdgcn_sched_barrier(0);

  int ca = 0;  // t % 3
  for (int t = 0; t < NT; ++t) {
    const int cb = t & 3;
    const bf16* Ac = As + ca * 8192 + aoff;
    const bf16* Bc = Bs + cb * 4096 + boff;
    const int na = ca + 2 >= 3 ? ca - 1 : ca + 2;   // (t+2)%3
    const int nb = (t + 3) & 3;

    // phase 0: A rows 0..3 x both B cols; stage A(t+2)
    bf16x8 a0[4], bf_[2];
    #pragma unroll
    for (int i = 0; i < 4; ++i) a0[i] = *(const bf16x8*)(Ac + i * 512);
    #pragma unroll
    for (int j = 0; j < 2; ++j) bf_[j] = *(const bf16x8*)(Bc + j * 512);
    if (t + 2 < NT) { STAGE_A((t + 2) * 32, na, 0); STAGE_A((t + 2) * 32, na, 1); }
    __builtin_amdgcn_s_setprio(1);
    #pragma unroll
    for (int i = 0; i < 4; ++i)
      #pragma unroll
      for (int j = 0; j < 2; ++j)
        acc[i][j] = __builtin_amdgcn_mfma_f32_16x16x32_bf16(a0[i], bf_[j], acc[i][j], 0, 0, 0);
    __builtin_amdgcn_s_setprio(0);

    // phase 1: A rows 4..7 (B frags reused); stage B(t+3)
    bf16x8 a1[4];
    #pragma unroll
    for (int i = 0; i < 4; ++i) a1[i] = *(const bf16x8*)(Ac + (i + 4) * 512);
    if (t + 3 < NT) STAGE_B((t + 3) * 32, nb);
    __builtin_amdgcn_s_setprio(1);
    #pragma unroll
    for (int i = 0; i < 4; ++i)
      #pragma unroll
      for (int j = 0; j < 2; ++j)
        acc[i + 4][j] = __builtin_amdgcn_mfma_f32_16x16x32_bf16(a1[i], bf_[j], acc[i + 4][j], 0, 0, 0);
    __builtin_amdgcn_s_setprio(0);

    if (t + 1 < NT) {
      if (t + 3 < NT)      { asm volatile("s_waitcnt vmcnt(4)" ::: "memory"); }
      else if (t + 2 < NT) { asm volatile("s_waitcnt vmcnt(3)" ::: "memory"); }
      else                 { asm volatile("s_waitcnt vmcnt(0)" ::: "memory"); }
      __builtin_amdgcn_sched_barrier(0);
      __builtin_amdgcn_s_barrier();
      __builtin_amdgcn_sched_barrier(0);
    }
    ca = (ca + 1 >= 3) ? 0 : ca + 1;
  }

  const int row0 = m0 + wm * 128 + q0 * 4;   // M (+i*16+r)
  const int col0 = n0 + wn * 32 + fr;        // N (+j*16)
  const long zo  = (long)b * Ostr;

  if constexpr (EPI == EPI_KF) {
    // kfT [n][kc] bf16: relu(acc*sc + bi), 8B stores (kc contiguous)
    bf16* op = (bf16*)Og + zo;
    #pragma unroll
    for (int i = 0; i < 8; ++i) {
      const int m = row0 + i * 16;
      float sc[4], bi[4];
      #pragma unroll
      for (int r = 0; r < 4; ++r) { sc[r] = ep0[m + r]; bi[r] = ep1[m + r]; }
      #pragma unroll
      for (int j = 0; j < 2; ++j) {
        bf16x4 pk;
        #pragma unroll
        for (int r = 0; r < 4; ++r)
          pk[r] = (bf16)fmaxf(acc[i][j][r] * sc[r] + bi[r], 0.0f);
        *(bf16x4*)(op + (long)(col0 + j * 16) * KCH + m) = pk;
      }
    }
  } else if constexpr (EPI == EPI_SBF) {
    bf16* op = (bf16*)Og + zo;   // write transposed [n][m] (S symmetric)
    #pragma unroll
    for (int i = 0; i < 8; ++i)
      #pragma unroll
      for (int j = 0; j < 2; ++j) {
        bf16x4 pk;
        #pragma unroll
        for (int r = 0; r < 4; ++r) pk[r] = (bf16)(acc[i][j][r] * 0.0625f);
        *(bf16x4*)(op + (long)(col0 + j * 16) * NSPAT + row0 + i * 16) = pk;
      }
  } else if constexpr (EPI == EPI_V1) {
    bf16* op = (bf16*)Og + zo;   // v1T [n][vc]
    #pragma unroll
    for (int i = 0; i < 8; ++i) {
      const int m = row0 + i * 16;
      #pragma unroll
      for (int j = 0; j < 2; ++j) {
        bf16x4 pk;
        #pragma unroll
        for (int r = 0; r < 4; ++r)
          pk[r] = (bf16)fmaxf(acc[i][j][r] + ep0[m + r], 0.0f);
        *(bf16x4*)(op + (long)(col0 + j * 16) * VCH + m) = pk;
      }
    }
  } else if constexpr (EPI == EPI_V) {
    bf16* op = (bf16*)Og + zo;   // v[m][n] row-major
    #pragma unroll
    for (int i = 0; i < 8; ++i)
      #pragma unroll
      for (int r = 0; r < 4; ++r) {
        const int m = row0 + i * 16 + r;
        const float bi = ep0[m];
        #pragma unroll
        for (int j = 0; j < 2; ++j)
          op[(long)m * NSPAT + col0 + j * 16] = (bf16)fmaxf(acc[i][j][r] + bi, 0.0f);
      }
  } else { // EPI_CTX: f32 [m][n]
    float* op = (float*)Og + zo;
    #pragma unroll
    for (int i = 0; i < 8; ++i)
      #pragma unroll
      for (int r = 0; r < 4; ++r) {
        const long base = (long)(row0 + i * 16 + r) * NSPAT;
        #pragma unroll
        for (int j = 0; j < 2; ++j)
          op[base + col0 + j * 16] = acc[i][j][r];
      }
  }
}

// ---------------------------------------------------------------------------
// legacy 128x128 kernel (fallback paths only)
template<int MODE, int EPI, int KDIM, int NY>
__global__ __launch_bounds__(256)
void k_gemm(const bf16* __restrict__ Ag, const void* __restrict__ Bg,
            void* __restrict__ Og, const float* __restrict__ ep0,
            const float* __restrict__ ep1,
            long Astr, long Bstr, long Ostr) {
  __shared__ bf16 As[2 * 128 * 32];
  __shared__ bf16 Bs[2 * 128 * 32];
  const int tid  = threadIdx.x;
  const int wave = tid >> 6;
  const int lane = tid & 63;
  const int b    = blockIdx.z;

  const int d  = blockIdx.x;
  const int xl = d & 7;
  const int y  = (d >> 3) % NY;
  const int xh = d / (8 * NY);
  const int n0 = (xh * 8 + xl) * 128;
  const int m0 = y * 128;

  const int rloc = lane >> 2;
  const int cswz = (lane & 3) ^ ((lane >> 3) & 3);
  const int colo = cswz * 8;
  const int r0   = wave * 32 + rloc;
  const int r1   = r0 + 16;

  const bf16* Ab  = Ag + (long)b * Astr;
  const bf16* ag0 = Ab + (long)(m0 + r0) * KDIM + colo;
  const bf16* ag1 = Ab + (long)(m0 + r1) * KDIM + colo;
  bf16* al0 = As + wave * 1024;
  bf16* al1 = As + wave * 1024 + 512;
  bf16* bl0 = Bs + wave * 1024;
  bf16* bl1 = Bs + wave * 1024 + 512;

  const bf16*  BbB = (const bf16*)Bg + (long)b * Bstr;
  const float* Sg  = (const float*)Bg + (long)b * Bstr;
  const bf16* bg0 = nullptr;
  const bf16* bg1 = nullptr;
  if constexpr (MODE == MODE_LIN) {
    bg0 = BbB + (long)(n0 + r0) * KDIM + colo;
    bg1 = BbB + (long)(n0 + r1) * KDIM + colo;
  } else if constexpr (MODE == MODE_PAD) {
    const int na = n0 + r0, nb = n0 + r1;
    bg0 = BbB + ((long)((na / WW + 1) * WPAD + (na % WW) + 1)) * CH + colo;
    bg1 = BbB + ((long)((nb / WW + 1) * WPAD + (nb % WW) + 1)) * CH + colo;
  }

  auto STAGE = [&](int k0, int buf) {
    const int o = buf << 12;
    gll16(ag0 + k0, al0 + o);
    gll16(ag1 + k0, al1 + o);
    if constexpr (MODE == MODE_LIN || MODE == MODE_PAD) {
      gll16(bg0 + k0, bl0 + o);
      gll16(bg1 + k0, bl1 + o);
    } else { // MODE_SIMF32
      #pragma unroll
      for (int p = 0; p < 4; ++p) {
        const int idx = p * 256 + tid;
        const int rr  = idx >> 3;
        const int cg  = (idx & 7) * 4;
        const float4 f = *(const float4*)(Sg + (long)(n0 + rr) * NSPAT + k0 + cg);
        bf16x4 hq;
        hq[0] = (bf16)f.x; hq[1] = (bf16)f.y; hq[2] = (bf16)f.z; hq[3] = (bf16)f.w;
        const int chunk = cg >> 3;
        const int swc   = (((chunk ^ ((rr >> 1) & 3)) << 3) | (cg & 7));
        *(bf16x4*)(Bs + o + rr * 32 + swc) = hq;
      }
    }
  };

  f32x4 acc[4][4] = {};

  const int wm = wave >> 1, wn = wave & 1;
  const int fr  = lane & 15;
  const int qsw = (((lane >> 4) ^ ((fr >> 1) & 3)) << 3);
  const bf16* ArF = As + (wm * 64 + fr) * 32 + qsw;
  const bf16* BrF = Bs + (wn * 64 + fr) * 32 + qsw;

  STAGE(0, 0);
  __syncthreads();
  int cur = 0;
  for (int k0 = 0; k0 < KDIM; k0 += 32) {
    if (k0 + 32 < KDIM) STAGE(k0 + 32, cur ^ 1);
    const int off = cur << 12;
    bf16x8 af[4], bfv[4];
    #pragma unroll
    for (int i = 0; i < 4; ++i) af[i] = *(const bf16x8*)(ArF + off + i * 512);
    #pragma unroll
    for (int j = 0; j < 4; ++j) bfv[j] = *(const bf16x8*)(BrF + off + j * 512);
    #pragma unroll
    for (int i = 0; i < 4; ++i)
      #pragma unroll
      for (int j = 0; j < 4; ++j)
        acc[i][j] = __builtin_amdgcn_mfma_f32_16x16x32_bf16(af[i], bfv[j], acc[i][j], 0, 0, 0);
    __syncthreads();
    cur ^= 1;
  }

  const int row0 = m0 + wm * 64 + (lane >> 4) * 4;
  const int col0 = n0 + wn * 64 + (lane & 15);
  const long zo  = (long)b * Ostr;

  if constexpr (EPI == EPI_KF) {
    bf16* op = (bf16*)Og + zo;
    #pragma unroll
    for (int i = 0; i < 4; ++i) {
      const int m = row0 + i * 16;
      float sc[4], bi[4];
      #pragma unroll
      for (int r = 0; r < 4; ++r) { sc[r] = ep0[m + r]; bi[r] = ep1[m + r]; }
      #pragma unroll
      for (int j = 0; j < 4; ++j) {
        const int n = col0 + j * 16;
        bf16x4 pk;
        #pragma unroll
        for (int r = 0; r < 4; ++r)
          pk[r] = (bf16)fmaxf(acc[i][j][r] * sc[r] + bi[r], 0.0f);
        *(bf16x4*)(op + (long)n * KCH + m) = pk;
      }
    }
  } else if constexpr (EPI == EPI_SF32) {
    float* op = (float*)Og + zo;
    #pragma unroll
    for (int i = 0; i < 4; ++i)
      #pragma unroll
      for (int j = 0; j < 4; ++j) {
        f32x4 sv = acc[i][j];
        sv[0] *= 0.0625f; sv[1] *= 0.0625f; sv[2] *= 0.0625f; sv[3] *= 0.0625f;
        *(f32x4*)(op + (long)(col0 + j * 16) * NSPAT + row0 + i * 16) = sv;
      }
  } else if constexpr (EPI == EPI_V) {
    bf16* op = (bf16*)Og + zo;   // v[m][n]
    #pragma unroll
    for (int i = 0; i < 4; ++i)
      #pragma unroll
      for (int r = 0; r < 4; ++r) {
        const int m = row0 + i * 16 + r;
        const float bi = ep0[m];
        #pragma unroll
        for (int j = 0; j < 4; ++j)
          op[(long)m * NSPAT + col0 + j * 16] = (bf16)fmaxf(acc[i][j][r] + bi, 0.0f);
      }
  } else { // EPI_CTX f32 [m][n]
    float* op = (float*)Og + zo;
    #pragma unroll
    for (int i = 0; i < 4; ++i)
      #pragma unroll
      for (int r = 0; r < 4; ++r) {
        const long base = (long)(row0 + i * 16 + r) * NSPAT;
        #pragma unroll
        for (int j = 0; j < 4; ++j)
          op[base + col0 + j * 16] = acc[i][j][r];
      }
  }
}

// x [B][C][H][W] f32 -> xpadT [B][NPAD][C] bf16, borders zeroed here.
__global__ __launch_bounds__(256)
void k_xpad(const float* __restrict__ x, bf16* __restrict__ xp) {
  __shared__ float t[64 * 81];
  const int cb  = blockIdx.x;
  const int hp  = blockIdx.y;
  const int b   = blockIdx.z;
  const int tid = threadIdx.x;
  const bool border = (hp == 0) || (hp == HPAD - 1);
  if (!border) {
    const float* xb = x + ((long)b * CH + cb * 64) * NSPAT + (hp - 1) * WW;
    for (int idx = tid; idx < 64 * 80; idx += 256) {
      const int cl = idx / 80;
      const int w  = idx - cl * 80;
      t[cl * 81 + w] = xb[(long)cl * NSPAT + w];
    }
    __syncthreads();
  }
  bf16* op = xp + ((long)b * NPAD + (long)hp * WPAD) * CH + cb * 64;
  for (int idx = tid; idx < WPAD * 64; idx += 256) {
    const int wp = idx >> 6;
    const int cl = idx & 63;
    float v = 0.0f;
    if (!border && wp >= 1 && wp <= WW) v = t[cl * 81 + (wp - 1)];
    op[(long)wp * CH + cl] = (bf16)v;
  }
}

__global__ void k_cvt(const float* __restrict__ in, bf16* __restrict__ out, int n) {
  const int i = blockIdx.x * 256 + threadIdx.x;
  if (i < n) out[i] = (bf16)in[i];
}

__global__ void k_cvt_wv1(const float* __restrict__ in, bf16* __restrict__ out) {
  const int o   = blockIdx.x * 256 + threadIdx.x;
  const int c   = o & 511;
  const int t2  = o >> 9;
  const int tap = t2 % 9;
  const int vc  = t2 / 9;
  out[o] = (bf16)in[((long)vc * 512 + c) * 9 + tap];
}

__global__ void k_bnp(const float* bk, const float* gamma, const float* beta,
                      const float* rmean, const float* rvar,
                      float* s, float* t) {
  const int k = threadIdx.x;
  const float sc = gamma[k] / sqrtf(rvar[k] + BN_EPS);
  s[k] = sc;
  t[k] = (bk[k] - rmean[k]) * sc + beta[k];
}

// read bf16 scores (16B loads), f32 softmax, write f32 sim (nontemporal, d_out)
// + bf16 sim in-place
__global__ __launch_bounds__(256)
void k_softmax_bf(bf16* __restrict__ Sb16, float* __restrict__ Sout) {
  const int tid = threadIdx.x;
  bf16*  p  = Sb16 + (long)blockIdx.x * NSPAT;
  float* po = Sout + (long)blockIdx.x * NSPAT;
  float v[20];
  float mx = -3.0e38f;
  {
    const bf16x8 h0 = *(const bf16x8*)(p + tid * 8);
    const bf16x8 h1 = *(const bf16x8*)(p + 2048 + tid * 8);
    const bf16x4 h2 = *(const bf16x4*)(p + 4096 + tid * 4);
    #pragma unroll
    for (int r = 0; r < 8; ++r) { v[r]     = (float)h0[r]; }
    #pragma unroll
    for (int r = 0; r < 8; ++r) { v[8 + r] = (float)h1[r]; }
    #pragma unroll
    for (int r = 0; r < 4; ++r) { v[16 + r] = (float)h2[r]; }
    #pragma unroll
    for (int e = 0; e < 20; ++e) mx = fmaxf(mx, v[e]);
  }
  __shared__ float red[4];
  #pragma unroll
  for (int o = 32; o > 0; o >>= 1) mx = fmaxf(mx, __shfl_xor(mx, o));
  if ((tid & 63) == 0) red[tid >> 6] = mx;
  __syncthreads();
  mx = fmaxf(fmaxf(red[0], red[1]), fmaxf(red[2], red[3]));
  float sum = 0.0f;
  #pragma unroll
  for (int e = 0; e < 20; ++e) { v[e] = __expf(v[e] - mx); sum += v[e]; }
  #pragma unroll
  for (int o = 32; o > 0; o >>= 1) sum += __shfl_xor(sum, o);
  __syncthreads();
  if ((tid & 63) == 0) red[tid >> 6] = sum;
  __syncthreads();
  sum = (red[0] + red[1]) + (red[2] + red[3]);
  const float inv = 1.0f / sum;
  #pragma unroll
  for (int e = 0; e < 20; ++e) v[e] *= inv;
  // f32 sim: nontemporal 16B stores (streamed output, never re-read)
  #pragma unroll
  for (int g = 0; g < 2; ++g) {
    #pragma unroll
    for (int h = 0; h < 2; ++h) {
      f32x4 o4;
      o4[0] = v[g * 8 + h * 4 + 0]; o4[1] = v[g * 8 + h * 4 + 1];
      o4[2] = v[g * 8 + h * 4 + 2]; o4[3] = v[g * 8 + h * 4 + 3];
      __builtin_nontemporal_store(o4, (f32x4*)(po + g * 2048 + tid * 8 + h * 4));
    }
  }
  {
    f32x4 o4;
    o4[0] = v[16]; o4[1] = v[17]; o4[2] = v[18]; o4[3] = v[19];
    __builtin_nontemporal_store(o4, (f32x4*)(po + 4096 + tid * 4));
  }
  // bf16 sim in-place: 16B + 8B stores
  {
    bf16x8 h0, h1;
    bf16x4 h2;
    #pragma unroll
    for (int r = 0; r < 8; ++r) { h0[r] = (bf16)v[r]; h1[r] = (bf16)v[8 + r]; }
    #pragma unroll
    for (int r = 0; r < 4; ++r) h2[r] = (bf16)v[16 + r];
    *(bf16x8*)(p + tid * 8) = h0;
    *(bf16x8*)(p + 2048 + tid * 8) = h1;
    *(bf16x4*)(p + 4096 + tid * 4) = h2;
  }
}

// fallback: f32 softmax in place
__global__ __launch_bounds__(256)
void k_softmax(float* __restrict__ S) {
  const int tid = threadIdx.x;
  float* p = S + (long)blockIdx.x * NSPAT;
  float4 v[5];
  float mx = -3.0e38f;
  #pragma unroll
  for (int q = 0; q < 5; ++q) {
    v[q] = *(const float4*)(p + (q * 256 + tid) * 4);
    mx = fmaxf(mx, fmaxf(fmaxf(v[q].x, v[q].y), fmaxf(v[q].z, v[q].w)));
  }
  __shared__ float red[4];
  #pragma unroll
  for (int o = 32; o > 0; o >>= 1) mx = fmaxf(mx, __shfl_xor(mx, o));
  if ((tid & 63) == 0) red[tid >> 6] = mx;
  __syncthreads();
  mx = fmaxf(fmaxf(red[0], red[1]), fmaxf(red[2], red[3]));
  float sum = 0.0f;
  #pragma unroll
  for (int q = 0; q < 5; ++q) {
    v[q].x = __expf(v[q].x - mx);
    v[q].y = __expf(v[q].y - mx);
    v[q].z = __expf(v[q].z - mx);
    v[q].w = __expf(v[q].w - mx);
    sum += (v[q].x + v[q].y) + (v[q].z + v[q].w);
  }
  #pragma unroll
  for (int o = 32; o > 0; o >>= 1) sum += __shfl_xor(sum, o);
  __syncthreads();
  if ((tid & 63) == 0) red[tid >> 6] = sum;
  __syncthreads();
  sum = (red[0] + red[1]) + (red[2] + red[3]);
  const float inv = 1.0f / sum;
  #pragma unroll
  for (int q = 0; q < 5; ++q) {
    float4 o4;
    o4.x = v[q].x * inv; o4.y = v[q].y * inv;
    o4.z = v[q].z * inv; o4.w = v[q].w * inv;
    *(float4*)(p + (q * 256 + tid) * 4) = o4;
  }
}

extern "C" void kernel_launch(void* const* d_in, const int* in_sizes, int n_in,
                              void* d_out, int out_size, void* d_ws, size_t ws_size,
                              hipStream_t stream) {
  const float* x     = (const float*)d_in[0];
  const float* wk    = (const float*)d_in[1];
  const float* bk    = (const float*)d_in[2];
  const float* gamma = (const float*)d_in[3];
  const float* beta  = (const float*)d_in[4];
  const float* rmean = (const float*)d_in[5];
  const float* rvar  = (const float*)d_in[6];
  const float* wv1   = (const float*)d_in[7];
  const float* bv1   = (const float*)d_in[8];
  const float* wv2   = (const float*)d_in[9];
  const float* bv2   = (const float*)d_in[10];

  float* ctx = (float*)d_out;                    // [B][VC][N]
  float* Sb  = ctx + (long)BATCH * VCH * NSPAT;  // [B][N][N] f32 sim output

  char* w = (char*)d_ws;
  auto alloc = [&](size_t bytes) {
    char* r = w;
    w += (bytes + 255) & ~(size_t)255;
    return r;
  };
  bf16*  xpadT = (bf16*)alloc((size_t)BATCH * NPAD * CH * 2);
  bf16*  kfT   = (bf16*)alloc((size_t)BATCH * NSPAT * KCH * 2);
  bf16*  v1T   = (bf16*)alloc((size_t)BATCH * NSPAT * VCH * 2);
  bf16*  vB    = (bf16*)alloc((size_t)BATCH * VCH * NSPAT * 2);
  bf16*  wkb   = (bf16*)alloc((size_t)KCH * CH * 2);
  bf16*  wv1b  = (bf16*)alloc((size_t)VCH * CH * 9 * 2);
  bf16*  wv2b  = (bf16*)alloc((size_t)VCH * VCH * 2);
  float* bnS   = (float*)alloc(KCH * 4);
  float* bnT   = (float*)alloc(KCH * 4);
  const size_t used = (size_t)(w - (char*)d_ws);
  if (ws_size < used) return;
  const size_t simbytes = (size_t)BATCH * NSPAT * NSPAT * 2;  // 209.7 MB
  bf16* simb = (ws_size - used >= simbytes) ? (bf16*)alloc(simbytes) : nullptr;

  k_xpad<<<dim3(8, HPAD, BATCH), 256, 0, stream>>>(x, xpadT);
  k_cvt<<<(KCH * CH) / 256, 256, 0, stream>>>(wk, wkb, KCH * CH);
  k_cvt_wv1<<<(VCH * CH * 9) / 256, 256, 0, stream>>>(wv1, wv1b);
  k_cvt<<<(VCH * VCH) / 256, 256, 0, stream>>>(wv2, wv2b, VCH * VCH);
  k_bnp<<<1, KCH, 0, stream>>>(bk, gamma, beta, rmean, rvar, bnS, bnT);

  // G1: kfT[b][n][kc] = relu(bn(wk . x))  (deep 256x128, one m-tile)
  k_gemm2<MODE_PAD, EPI_KF, CH, 0><<<dim3(40, 1, BATCH), 512, 0, stream>>>(
      wkb, xpadT, kfT, bnS, bnT, 0, (long)NPAD * CH, (long)NSPAT * KCH, 40);
  // G3: v1T[b][n][vc] = relu(conv3x3(x))  (deep 256x128, asym ring)
  k_gemm2<MODE_CONV, EPI_V1, CH * 9, 1><<<dim3(80, 1, BATCH), 512, 0, stream>>>(
      wv1b, xpadT, v1T, bv1, nullptr, 0, (long)NPAD * CH, (long)NSPAT * VCH, 40);
  // G4: v[b][vc][n] = relu(wv2 . v1)
  k_gemm2<MODE_LIN, EPI_V, VCH, 1><<<dim3(80, 1, BATCH), 512, 0, stream>>>(
      wv2b, v1T, vB, bv2, nullptr, 0, (long)NSPAT * VCH, (long)VCH * NSPAT, 40);

  if (simb) {
    // G2: bf16 scores -> simb (transposed-symmetric write), 800 blocks/batch
    k_gemm2<MODE_LIN, EPI_SBF, KCH, 0><<<dim3(20 * 40, 1, BATCH), 512, 0, stream>>>(
        kfT, kfT, simb, nullptr, nullptr, (long)NSPAT * KCH, (long)NSPAT * KCH, (long)NSPAT * NSPAT, 40);
    k_softmax_bf<<<BATCH * NSPAT, 256, 0, stream>>>(simb, Sb);
    // G5: context = v . sim^T  (deep, B=sim gets ring-4 latency slack)
    k_gemm2<MODE_LIN, EPI_CTX, NSPAT, 1><<<dim3(80, 1, BATCH), 512, 0, stream>>>(
        vB, simb, ctx, nullptr, nullptr, (long)VCH * NSPAT, (long)NSPAT * NSPAT, (long)VCH * NSPAT, 40);
  } else {
    // fallback: f32 scores -> d_out sim region, in-place softmax, f32-staged G5
    k_gemm<MODE_LIN, EPI_SF32, KCH, 40><<<dim3(40 * 40, 1, BATCH), 256, 0, stream>>>(
        kfT, kfT, Sb, nullptr, nullptr, (long)NSPAT * KCH, (long)NSPAT * KCH, (long)NSPAT * NSPAT);
    k_softmax<<<BATCH * NSPAT, 256, 0, stream>>>(Sb);
    k_gemm<MODE_SIMF32, EPI_CTX, NSPAT, 4><<<dim3(40 * 4, 1, BATCH), 256, 0, stream>>>(
        vB, Sb, ctx, nullptr, nullptr, (long)VCH * NSPAT, (long)NSPAT * NSPAT, (long)VCH * NSPAT);
  }
}

// Round 15
// 607.164 us; speedup vs baseline: 1.1453x; 1.0068x over previous
//
#include <hip/hip_runtime.h>
#include <hip/hip_bf16.h>
#include <stdint.h>

typedef __bf16 bf16;
typedef __bf16 bf16x8 __attribute__((ext_vector_type(8)));
typedef __bf16 bf16x4 __attribute__((ext_vector_type(4)));
typedef float f32x4 __attribute__((ext_vector_type(4)));

static constexpr int BATCH = 4;
static constexpr int CH    = 512;
static constexpr int HH    = 64;
static constexpr int WW    = 80;
static constexpr int NSPAT = HH * WW;       // 5120
static constexpr int KCH   = 256;
static constexpr int VCH   = 512;
static constexpr int HPAD  = HH + 2;        // 66
static constexpr int WPAD  = WW + 2;        // 82
static constexpr int NPAD  = HPAD * WPAD;   // 5412
static constexpr float BN_EPS = 1e-5f;

enum { MODE_LIN = 0, MODE_PAD = 1, MODE_CONV = 2, MODE_SIMF32 = 3 };
enum { EPI_KF = 0, EPI_SBF = 1, EPI_SF32 = 2, EPI_V1 = 3, EPI_V = 4, EPI_CTX = 5, EPI_CTXT = 6 };

__device__ __forceinline__ void gll16(const void* g, void* l) {
  __builtin_amdgcn_global_load_lds((const __attribute__((address_space(1))) void*)g,
                                   (__attribute__((address_space(3))) void*)l,
                                   16, 0, 0);
}

// ---------------------------------------------------------------------------
// k_gemm2 (R7-verified): deep-pipelined GEMM, asymmetric ring depth.
// C[M,N] = A[M,K]*B[N,K]^T, bf16 in, f32 acc. BM=256, BN=128, BK=32,
// 512 threads (8 waves 2Mx4N), per-wave out 128x32.
// LDS: A ring-3 (3x16KB) + B ring-4 (4x8KB) = 80 KiB -> 2 blocks/CU.
// Counted-vmcnt ledger: steady vmcnt(4), tails vmcnt(3)/vmcnt(0).
// REMAP=1: m-pair of one n-tile share an XCD (B-panel L2 reuse).
// REMAP=2 (G5-swapped, grid.x=320, z=1): d -> XCD=d&7 gets 10 consecutive
//   (b,m)-panels, each with its 4 n-blocks co-XCD -> A panel (2.62 MB) is
//   fetched ~once per XCD and stays L2-hot; B (vB, 5.2 MB/batch) L2-hot.
template<int MODE, int EPI, int KDIM, int REMAP>
__global__ __launch_bounds__(512, 4)
void k_gemm2(const bf16* __restrict__ Ag, const void* __restrict__ Bg,
             void* __restrict__ Og, const float* __restrict__ ep0,
             const float* __restrict__ ep1,
             long Astr, long Bstr, long Ostr, int ntn) {
  __shared__ bf16 As[3 * 8192];   // ring-3 of 256x32
  __shared__ bf16 Bs[4 * 4096];   // ring-4 of 128x32
  constexpr int NT = KDIM / 32;
  static_assert(NT >= 4, "pipeline needs >=4 K-tiles");
  const int tid  = threadIdx.x;
  const int wave = tid >> 6;
  const int lane = tid & 63;
  int b = blockIdx.z;

  int m_t, n_t;
  if constexpr (REMAP == 1) {
    // 80 blocks/batch: pair (m0,m1) of one n-tile share an XCD (B-panel L2).
    const int d = blockIdx.x;
    const int xl = d & 7, r = d >> 3;
    m_t = r & 1;
    n_t = (r >> 1) * 8 + xl;
  } else if constexpr (REMAP == 2) {
    // flattened d in [0,320): XCD=d&7; s=d>>3 in [0,40);
    // panel = (d&7)*10 + (s>>2) in [0,80) -> (b, m_t); n_t = s&3. Bijective.
    const int d = blockIdx.x;
    const int s = d >> 3;
    const int panel = (d & 7) * 10 + (s >> 2);
    b   = panel / 20;
    m_t = panel % 20;
    n_t = s & 3;
  } else {
    m_t = blockIdx.x / ntn;
    n_t = blockIdx.x % ntn;
  }
  const int m0 = m_t * 256, n0 = n_t * 128;

  const int srow = tid >> 2;
  const int gq   = (tid & 3) ^ ((tid >> 3) & 3);
  const bf16* Ab = Ag + (long)b * Astr;
  const bf16* aS = Ab + (long)(m0 + srow) * KDIM + gq * 8;
  const bf16* BbB = (const bf16*)Bg + (long)b * Bstr;
  const bf16* bS = nullptr;
  int bsp = 0;
  if constexpr (MODE == MODE_LIN) {
    bS = BbB + (long)(n0 + srow) * KDIM + gq * 8;
  } else if constexpr (MODE == MODE_PAD) {
    const int nb = n0 + srow;
    bS = BbB + ((long)((nb / WW + 1) * WPAD + (nb % WW) + 1)) * CH + gq * 8;
  } else { // MODE_CONV
    const int nb = n0 + srow;
    bsp = (nb / WW) * WPAD + (nb % WW);
  }

  auto STAGE_A = [&](int k0, int buf, int s) {
    gll16(aS + (long)s * (128 * KDIM) + k0, As + buf * 8192 + s * 4096 + tid * 8);
  };
  auto STAGE_B = [&](int k0, int buf) {
    if constexpr (MODE == MODE_LIN || MODE == MODE_PAD) {
      gll16(bS + k0, Bs + buf * 4096 + tid * 8);
    } else {
      const int tap = k0 >> 9, within = k0 & 511;
      const int kh = tap / 3, kw = tap - kh * 3;
      const int off = kh * WPAD + kw;
      gll16(BbB + (long)(bsp + off) * CH + within + gq * 8, Bs + buf * 4096 + tid * 8);
    }
  };

  const int fr = lane & 15, q0 = lane >> 4;
  const int wm = wave >> 2, wn = wave & 3;
  const int ksw  = ((q0 ^ ((fr >> 1) & 3))) * 8;
  const int aoff = (wm * 128 + fr) * 32 + ksw;
  const int boff = (wn * 32 + fr) * 32 + ksw;

  f32x4 acc[8][2] = {};

  // prologue: A(0),A(1); B(0),B(1),B(2). wait keeps {A1a,A1b,B1,B2}.
  STAGE_A(0, 0, 0); STAGE_A(0, 0, 1); STAGE_B(0, 0);
  STAGE_A(32, 1, 0); STAGE_A(32, 1, 1); STAGE_B(32, 1);
  if (2 < NT) STAGE_B(64, 2);
  asm volatile("s_waitcnt vmcnt(4)" ::: "memory");
  __builtin_amdgcn_sched_barrier(0);
  __builtin_amdgcn_s_barrier();
  __builtin_amdgcn_sched_barrier(0);

  int ca = 0;  // t % 3
  for (int t = 0; t < NT; ++t) {
    const int cb = t & 3;
    const bf16* Ac = As + ca * 8192 + aoff;
    const bf16* Bc = Bs + cb * 4096 + boff;
    const int na = ca + 2 >= 3 ? ca - 1 : ca + 2;   // (t+2)%3
    const int nb = (t + 3) & 3;

    // phase 0: A rows 0..3 x both B cols; stage A(t+2)
    bf16x8 a0[4], bf_[2];
    #pragma unroll
    for (int i = 0; i < 4; ++i) a0[i] = *(const bf16x8*)(Ac + i * 512);
    #pragma unroll
    for (int j = 0; j < 2; ++j) bf_[j] = *(const bf16x8*)(Bc + j * 512);
    if (t + 2 < NT) { STAGE_A((t + 2) * 32, na, 0); STAGE_A((t + 2) * 32, na, 1); }
    __builtin_amdgcn_s_setprio(1);
    #pragma unroll
    for (int i = 0; i < 4; ++i)
      #pragma unroll
      for (int j = 0; j < 2; ++j)
        acc[i][j] = __builtin_amdgcn_mfma_f32_16x16x32_bf16(a0[i], bf_[j], acc[i][j], 0, 0, 0);
    __builtin_amdgcn_s_setprio(0);

    // phase 1: A rows 4..7 (B frags reused); stage B(t+3)
    bf16x8 a1[4];
    #pragma unroll
    for (int i = 0; i < 4; ++i) a1[i] = *(const bf16x8*)(Ac + (i + 4) * 512);
    if (t + 3 < NT) STAGE_B((t + 3) * 32, nb);
    __builtin_amdgcn_s_setprio(1);
    #pragma unroll
    for (int i = 0; i < 4; ++i)
      #pragma unroll
      for (int j = 0; j < 2; ++j)
        acc[i + 4][j] = __builtin_amdgcn_mfma_f32_16x16x32_bf16(a1[i], bf_[j], acc[i + 4][j], 0, 0, 0);
    __builtin_amdgcn_s_setprio(0);

    if (t + 1 < NT) {
      if (t + 3 < NT)      { asm volatile("s_waitcnt vmcnt(4)" ::: "memory"); }
      else if (t + 2 < NT) { asm volatile("s_waitcnt vmcnt(3)" ::: "memory"); }
      else                 { asm volatile("s_waitcnt vmcnt(0)" ::: "memory"); }
      __builtin_amdgcn_sched_barrier(0);
      __builtin_amdgcn_s_barrier();
      __builtin_amdgcn_sched_barrier(0);
    }
    ca = (ca + 1 >= 3) ? 0 : ca + 1;
  }

  const int row0 = m0 + wm * 128 + q0 * 4;   // M (+i*16+r)
  const int col0 = n0 + wn * 32 + fr;        // N (+j*16)
  const long zo  = (long)b * Ostr;

  if constexpr (EPI == EPI_KF) {
    bf16* op = (bf16*)Og + zo;
    #pragma unroll
    for (int i = 0; i < 8; ++i) {
      const int m = row0 + i * 16;
      float sc[4], bi[4];
      #pragma unroll
      for (int r = 0; r < 4; ++r) { sc[r] = ep0[m + r]; bi[r] = ep1[m + r]; }
      #pragma unroll
      for (int j = 0; j < 2; ++j) {
        bf16x4 pk;
        #pragma unroll
        for (int r = 0; r < 4; ++r)
          pk[r] = (bf16)fmaxf(acc[i][j][r] * sc[r] + bi[r], 0.0f);
        *(bf16x4*)(op + (long)(col0 + j * 16) * KCH + m) = pk;
      }
    }
  } else if constexpr (EPI == EPI_SBF) {
    bf16* op = (bf16*)Og + zo;   // write transposed [n][m] (S symmetric)
    #pragma unroll
    for (int i = 0; i < 8; ++i)
      #pragma unroll
      for (int j = 0; j < 2; ++j) {
        bf16x4 pk;
        #pragma unroll
        for (int r = 0; r < 4; ++r) pk[r] = (bf16)(acc[i][j][r] * 0.0625f);
        *(bf16x4*)(op + (long)(col0 + j * 16) * NSPAT + row0 + i * 16) = pk;
      }
  } else if constexpr (EPI == EPI_V1) {
    bf16* op = (bf16*)Og + zo;   // v1T [n][vc]
    #pragma unroll
    for (int i = 0; i < 8; ++i) {
      const int m = row0 + i * 16;
      #pragma unroll
      for (int j = 0; j < 2; ++j) {
        bf16x4 pk;
        #pragma unroll
        for (int r = 0; r < 4; ++r)
          pk[r] = (bf16)fmaxf(acc[i][j][r] + ep0[m + r], 0.0f);
        *(bf16x4*)(op + (long)(col0 + j * 16) * VCH + m) = pk;
      }
    }
  } else if constexpr (EPI == EPI_V) {
    bf16* op = (bf16*)Og + zo;   // v[m][n] row-major
    #pragma unroll
    for (int i = 0; i < 8; ++i)
      #pragma unroll
      for (int r = 0; r < 4; ++r) {
        const int m = row0 + i * 16 + r;
        const float bi = ep0[m];
        #pragma unroll
        for (int j = 0; j < 2; ++j)
          op[(long)m * NSPAT + col0 + j * 16] = (bf16)fmaxf(acc[i][j][r] + bi, 0.0f);
      }
  } else if constexpr (EPI == EPI_CTXT) {
    // GEMM-row = spatial n, GEMM-col = vc; ctx[vc][spatial]: 16B f32x4 stores
    float* op = (float*)Og + zo;
    #pragma unroll
    for (int i = 0; i < 8; ++i)
      #pragma unroll
      for (int j = 0; j < 2; ++j)
        *(f32x4*)(op + (long)(col0 + j * 16) * NSPAT + row0 + i * 16) = acc[i][j];
  } else { // EPI_CTX: f32 [m][n]
    float* op = (float*)Og + zo;
    #pragma unroll
    for (int i = 0; i < 8; ++i)
      #pragma unroll
      for (int r = 0; r < 4; ++r) {
        const long base = (long)(row0 + i * 16 + r) * NSPAT;
        #pragma unroll
        for (int j = 0; j < 2; ++j)
          op[base + col0 + j * 16] = acc[i][j][r];
      }
  }
}

// ---------------------------------------------------------------------------
// legacy 128x128 kernel (fallback paths only)
template<int MODE, int EPI, int KDIM, int NY>
__global__ __launch_bounds__(256)
void k_gemm(const bf16* __restrict__ Ag, const void* __restrict__ Bg,
            void* __restrict__ Og, const float* __restrict__ ep0,
            const float* __restrict__ ep1,
            long Astr, long Bstr, long Ostr) {
  __shared__ bf16 As[2 * 128 * 32];
  __shared__ bf16 Bs[2 * 128 * 32];
  const int tid  = threadIdx.x;
  const int wave = tid >> 6;
  const int lane = tid & 63;
  const int b    = blockIdx.z;

  const int d  = blockIdx.x;
  const int xl = d & 7;
  const int y  = (d >> 3) % NY;
  const int xh = d / (8 * NY);
  const int n0 = (xh * 8 + xl) * 128;
  const int m0 = y * 128;

  const int rloc = lane >> 2;
  const int cswz = (lane & 3) ^ ((lane >> 3) & 3);
  const int colo = cswz * 8;
  const int r0   = wave * 32 + rloc;
  const int r1   = r0 + 16;

  const bf16* Ab  = Ag + (long)b * Astr;
  const bf16* ag0 = Ab + (long)(m0 + r0) * KDIM + colo;
  const bf16* ag1 = Ab + (long)(m0 + r1) * KDIM + colo;
  bf16* al0 = As + wave * 1024;
  bf16* al1 = As + wave * 1024 + 512;
  bf16* bl0 = Bs + wave * 1024;
  bf16* bl1 = Bs + wave * 1024 + 512;

  const bf16*  BbB = (const bf16*)Bg + (long)b * Bstr;
  const float* Sg  = (const float*)Bg + (long)b * Bstr;
  const bf16* bg0 = nullptr;
  const bf16* bg1 = nullptr;
  if constexpr (MODE == MODE_LIN) {
    bg0 = BbB + (long)(n0 + r0) * KDIM + colo;
    bg1 = BbB + (long)(n0 + r1) * KDIM + colo;
  } else if constexpr (MODE == MODE_PAD) {
    const int na = n0 + r0, nb = n0 + r1;
    bg0 = BbB + ((long)((na / WW + 1) * WPAD + (na % WW) + 1)) * CH + colo;
    bg1 = BbB + ((long)((nb / WW + 1) * WPAD + (nb % WW) + 1)) * CH + colo;
  }

  auto STAGE = [&](int k0, int buf) {
    const int o = buf << 12;
    gll16(ag0 + k0, al0 + o);
    gll16(ag1 + k0, al1 + o);
    if constexpr (MODE == MODE_LIN || MODE == MODE_PAD) {
      gll16(bg0 + k0, bl0 + o);
      gll16(bg1 + k0, bl1 + o);
    } else { // MODE_SIMF32
      #pragma unroll
      for (int p = 0; p < 4; ++p) {
        const int idx = p * 256 + tid;
        const int rr  = idx >> 3;
        const int cg  = (idx & 7) * 4;
        const float4 f = *(const float4*)(Sg + (long)(n0 + rr) * NSPAT + k0 + cg);
        bf16x4 hq;
        hq[0] = (bf16)f.x; hq[1] = (bf16)f.y; hq[2] = (bf16)f.z; hq[3] = (bf16)f.w;
        const int chunk = cg >> 3;
        const int swc   = (((chunk ^ ((rr >> 1) & 3)) << 3) | (cg & 7));
        *(bf16x4*)(Bs + o + rr * 32 + swc) = hq;
      }
    }
  };

  f32x4 acc[4][4] = {};

  const int wm = wave >> 1, wn = wave & 1;
  const int fr  = lane & 15;
  const int qsw = (((lane >> 4) ^ ((fr >> 1) & 3)) << 3);
  const bf16* ArF = As + (wm * 64 + fr) * 32 + qsw;
  const bf16* BrF = Bs + (wn * 64 + fr) * 32 + qsw;

  STAGE(0, 0);
  __syncthreads();
  int cur = 0;
  for (int k0 = 0; k0 < KDIM; k0 += 32) {
    if (k0 + 32 < KDIM) STAGE(k0 + 32, cur ^ 1);
    const int off = cur << 12;
    bf16x8 af[4], bfv[4];
    #pragma unroll
    for (int i = 0; i < 4; ++i) af[i] = *(const bf16x8*)(ArF + off + i * 512);
    #pragma unroll
    for (int j = 0; j < 4; ++j) bfv[j] = *(const bf16x8*)(BrF + off + j * 512);
    #pragma unroll
    for (int i = 0; i < 4; ++i)
      #pragma unroll
      for (int j = 0; j < 4; ++j)
        acc[i][j] = __builtin_amdgcn_mfma_f32_16x16x32_bf16(af[i], bfv[j], acc[i][j], 0, 0, 0);
    __syncthreads();
    cur ^= 1;
  }

  const int row0 = m0 + wm * 64 + (lane >> 4) * 4;
  const int col0 = n0 + wn * 64 + (lane & 15);
  const long zo  = (long)b * Ostr;

  if constexpr (EPI == EPI_KF) {
    bf16* op = (bf16*)Og + zo;
    #pragma unroll
    for (int i = 0; i < 4; ++i) {
      const int m = row0 + i * 16;
      float sc[4], bi[4];
      #pragma unroll
      for (int r = 0; r < 4; ++r) { sc[r] = ep0[m + r]; bi[r] = ep1[m + r]; }
      #pragma unroll
      for (int j = 0; j < 4; ++j) {
        const int n = col0 + j * 16;
        bf16x4 pk;
        #pragma unroll
        for (int r = 0; r < 4; ++r)
          pk[r] = (bf16)fmaxf(acc[i][j][r] * sc[r] + bi[r], 0.0f);
        *(bf16x4*)(op + (long)n * KCH + m) = pk;
      }
    }
  } else if constexpr (EPI == EPI_SF32) {
    float* op = (float*)Og + zo;
    #pragma unroll
    for (int i = 0; i < 4; ++i)
      #pragma unroll
      for (int j = 0; j < 4; ++j) {
        f32x4 sv = acc[i][j];
        sv[0] *= 0.0625f; sv[1] *= 0.0625f; sv[2] *= 0.0625f; sv[3] *= 0.0625f;
        *(f32x4*)(op + (long)(col0 + j * 16) * NSPAT + row0 + i * 16) = sv;
      }
  } else if constexpr (EPI == EPI_V) {
    bf16* op = (bf16*)Og + zo;   // v[m][n]
    #pragma unroll
    for (int i = 0; i < 4; ++i)
      #pragma unroll
      for (int r = 0; r < 4; ++r) {
        const int m = row0 + i * 16 + r;
        const float bi = ep0[m];
        #pragma unroll
        for (int j = 0; j < 4; ++j)
          op[(long)m * NSPAT + col0 + j * 16] = (bf16)fmaxf(acc[i][j][r] + bi, 0.0f);
      }
  } else { // EPI_CTX f32 [m][n]
    float* op = (float*)Og + zo;
    #pragma unroll
    for (int i = 0; i < 4; ++i)
      #pragma unroll
      for (int r = 0; r < 4; ++r) {
        const long base = (long)(row0 + i * 16 + r) * NSPAT;
        #pragma unroll
        for (int j = 0; j < 4; ++j)
          op[base + col0 + j * 16] = acc[i][j][r];
      }
  }
}

// x [B][C][H][W] f32 -> xpadT [B][NPAD][C] bf16, borders zeroed here.
__global__ __launch_bounds__(256)
void k_xpad(const float* __restrict__ x, bf16* __restrict__ xp) {
  __shared__ float t[64 * 81];
  const int cb  = blockIdx.x;
  const int hp  = blockIdx.y;
  const int b   = blockIdx.z;
  const int tid = threadIdx.x;
  const bool border = (hp == 0) || (hp == HPAD - 1);
  if (!border) {
    const float* xb = x + ((long)b * CH + cb * 64) * NSPAT + (hp - 1) * WW;
    for (int idx = tid; idx < 64 * 80; idx += 256) {
      const int cl = idx / 80;
      const int w  = idx - cl * 80;
      t[cl * 81 + w] = xb[(long)cl * NSPAT + w];
    }
    __syncthreads();
  }
  bf16* op = xp + ((long)b * NPAD + (long)hp * WPAD) * CH + cb * 64;
  for (int idx = tid; idx < WPAD * 64; idx += 256) {
    const int wp = idx >> 6;
    const int cl = idx & 63;
    float v = 0.0f;
    if (!border && wp >= 1 && wp <= WW) v = t[cl * 81 + (wp - 1)];
    op[(long)wp * CH + cl] = (bf16)v;
  }
}

__global__ void k_cvt(const float* __restrict__ in, bf16* __restrict__ out, int n) {
  const int i = blockIdx.x * 256 + threadIdx.x;
  if (i < n) out[i] = (bf16)in[i];
}

__global__ void k_cvt_wv1(const float* __restrict__ in, bf16* __restrict__ out) {
  const int o   = blockIdx.x * 256 + threadIdx.x;
  const int c   = o & 511;
  const int t2  = o >> 9;
  const int tap = t2 % 9;
  const int vc  = t2 / 9;
  out[o] = (bf16)in[((long)vc * 512 + c) * 9 + tap];
}

__global__ void k_bnp(const float* bk, const float* gamma, const float* beta,
                      const float* rmean, const float* rvar,
                      float* s, float* t) {
  const int k = threadIdx.x;
  const float sc = gamma[k] / sqrtf(rvar[k] + BN_EPS);
  s[k] = sc;
  t[k] = (bk[k] - rmean[k]) * sc + beta[k];
}

// read bf16 scores (16B loads), f32 softmax, write f32 sim (nontemporal, d_out)
// + bf16 sim in-place
__global__ __launch_bounds__(256)
void k_softmax_bf(bf16* __restrict__ Sb16, float* __restrict__ Sout) {
  const int tid = threadIdx.x;
  bf16*  p  = Sb16 + (long)blockIdx.x * NSPAT;
  float* po = Sout + (long)blockIdx.x * NSPAT;
  float v[20];
  float mx = -3.0e38f;
  {
    const bf16x8 h0 = *(const bf16x8*)(p + tid * 8);
    const bf16x8 h1 = *(const bf16x8*)(p + 2048 + tid * 8);
    const bf16x4 h2 = *(const bf16x4*)(p + 4096 + tid * 4);
    #pragma unroll
    for (int r = 0; r < 8; ++r) { v[r]     = (float)h0[r]; }
    #pragma unroll
    for (int r = 0; r < 8; ++r) { v[8 + r] = (float)h1[r]; }
    #pragma unroll
    for (int r = 0; r < 4; ++r) { v[16 + r] = (float)h2[r]; }
    #pragma unroll
    for (int e = 0; e < 20; ++e) mx = fmaxf(mx, v[e]);
  }
  __shared__ float red[4];
  #pragma unroll
  for (int o = 32; o > 0; o >>= 1) mx = fmaxf(mx, __shfl_xor(mx, o));
  if ((tid & 63) == 0) red[tid >> 6] = mx;
  __syncthreads();
  mx = fmaxf(fmaxf(red[0], red[1]), fmaxf(red[2], red[3]));
  float sum = 0.0f;
  #pragma unroll
  for (int e = 0; e < 20; ++e) { v[e] = __expf(v[e] - mx); sum += v[e]; }
  #pragma unroll
  for (int o = 32; o > 0; o >>= 1) sum += __shfl_xor(sum, o);
  __syncthreads();
  if ((tid & 63) == 0) red[tid >> 6] = sum;
  __syncthreads();
  sum = (red[0] + red[1]) + (red[2] + red[3]);
  const float inv = 1.0f / sum;
  #pragma unroll
  for (int e = 0; e < 20; ++e) v[e] *= inv;
  // f32 sim: nontemporal 16B stores (streamed output, never re-read)
  #pragma unroll
  for (int g = 0; g < 2; ++g) {
    #pragma unroll
    for (int h = 0; h < 2; ++h) {
      f32x4 o4;
      o4[0] = v[g * 8 + h * 4 + 0]; o4[1] = v[g * 8 + h * 4 + 1];
      o4[2] = v[g * 8 + h * 4 + 2]; o4[3] = v[g * 8 + h * 4 + 3];
      __builtin_nontemporal_store(o4, (f32x4*)(po + g * 2048 + tid * 8 + h * 4));
    }
  }
  {
    f32x4 o4;
    o4[0] = v[16]; o4[1] = v[17]; o4[2] = v[18]; o4[3] = v[19];
    __builtin_nontemporal_store(o4, (f32x4*)(po + 4096 + tid * 4));
  }
  // bf16 sim in-place: 16B + 8B stores
  {
    bf16x8 h0, h1;
    bf16x4 h2;
    #pragma unroll
    for (int r = 0; r < 8; ++r) { h0[r] = (bf16)v[r]; h1[r] = (bf16)v[8 + r]; }
    #pragma unroll
    for (int r = 0; r < 4; ++r) h2[r] = (bf16)v[16 + r];
    *(bf16x8*)(p + tid * 8) = h0;
    *(bf16x8*)(p + 2048 + tid * 8) = h1;
    *(bf16x4*)(p + 4096 + tid * 4) = h2;
  }
}

// fallback: f32 softmax in place
__global__ __launch_bounds__(256)
void k_softmax(float* __restrict__ S) {
  const int tid = threadIdx.x;
  float* p = S + (long)blockIdx.x * NSPAT;
  float4 v[5];
  float mx = -3.0e38f;
  #pragma unroll
  for (int q = 0; q < 5; ++q) {
    v[q] = *(const float4*)(p + (q * 256 + tid) * 4);
    mx = fmaxf(mx, fmaxf(fmaxf(v[q].x, v[q].y), fmaxf(v[q].z, v[q].w)));
  }
  __shared__ float red[4];
  #pragma unroll
  for (int o = 32; o > 0; o >>= 1) mx = fmaxf(mx, __shfl_xor(mx, o));
  if ((tid & 63) == 0) red[tid >> 6] = mx;
  __syncthreads();
  mx = fmaxf(fmaxf(red[0], red[1]), fmaxf(red[2], red[3]));
  float sum = 0.0f;
  #pragma unroll
  for (int q = 0; q < 5; ++q) {
    v[q].x = __expf(v[q].x - mx);
    v[q].y = __expf(v[q].y - mx);
    v[q].z = __expf(v[q].z - mx);
    v[q].w = __expf(v[q].w - mx);
    sum += (v[q].x + v[q].y) + (v[q].z + v[q].w);
  }
  #pragma unroll
  for (int o = 32; o > 0; o >>= 1) sum += __shfl_xor(sum, o);
  __syncthreads();
  if ((tid & 63) == 0) red[tid >> 6] = sum;
  __syncthreads();
  sum = (red[0] + red[1]) + (red[2] + red[3]);
  const float inv = 1.0f / sum;
  #pragma unroll
  for (int q = 0; q < 5; ++q) {
    float4 o4;
    o4.x = v[q].x * inv; o4.y = v[q].y * inv;
    o4.z = v[q].z * inv; o4.w = v[q].w * inv;
    *(float4*)(p + (q * 256 + tid) * 4) = o4;
  }
}

extern "C" void kernel_launch(void* const* d_in, const int* in_sizes, int n_in,
                              void* d_out, int out_size, void* d_ws, size_t ws_size,
                              hipStream_t stream) {
  const float* x     = (const float*)d_in[0];
  const float* wk    = (const float*)d_in[1];
  const float* bk    = (const float*)d_in[2];
  const float* gamma = (const float*)d_in[3];
  const float* beta  = (const float*)d_in[4];
  const float* rmean = (const float*)d_in[5];
  const float* rvar  = (const float*)d_in[6];
  const float* wv1   = (const float*)d_in[7];
  const float* bv1   = (const float*)d_in[8];
  const float* wv2   = (const float*)d_in[9];
  const float* bv2   = (const float*)d_in[10];

  float* ctx = (float*)d_out;                    // [B][VC][N]
  float* Sb  = ctx + (long)BATCH * VCH * NSPAT;  // [B][N][N] f32 sim output

  char* w = (char*)d_ws;
  auto alloc = [&](size_t bytes) {
    char* r = w;
    w += (bytes + 255) & ~(size_t)255;
    return r;
  };
  bf16*  xpadT = (bf16*)alloc((size_t)BATCH * NPAD * CH * 2);
  bf16*  kfT   = (bf16*)alloc((size_t)BATCH * NSPAT * KCH * 2);
  bf16*  v1T   = (bf16*)alloc((size_t)BATCH * NSPAT * VCH * 2);
  bf16*  vB    = (bf16*)alloc((size_t)BATCH * VCH * NSPAT * 2);
  bf16*  wkb   = (bf16*)alloc((size_t)KCH * CH * 2);
  bf16*  wv1b  = (bf16*)alloc((size_t)VCH * CH * 9 * 2);
  bf16*  wv2b  = (bf16*)alloc((size_t)VCH * VCH * 2);
  float* bnS   = (float*)alloc(KCH * 4);
  float* bnT   = (float*)alloc(KCH * 4);
  const size_t used = (size_t)(w - (char*)d_ws);
  if (ws_size < used) return;
  const size_t simbytes = (size_t)BATCH * NSPAT * NSPAT * 2;  // 209.7 MB
  bf16* simb = (ws_size - used >= simbytes) ? (bf16*)alloc(simbytes) : nullptr;

  k_xpad<<<dim3(8, HPAD, BATCH), 256, 0, stream>>>(x, xpadT);
  k_cvt<<<(KCH * CH) / 256, 256, 0, stream>>>(wk, wkb, KCH * CH);
  k_cvt_wv1<<<(VCH * CH * 9) / 256, 256, 0, stream>>>(wv1, wv1b);
  k_cvt<<<(VCH * VCH) / 256, 256, 0, stream>>>(wv2, wv2b, VCH * VCH);
  k_bnp<<<1, KCH, 0, stream>>>(bk, gamma, beta, rmean, rvar, bnS, bnT);

  // G1: kfT[b][n][kc] = relu(bn(wk . x))  (deep 256x128, one m-tile)
  k_gemm2<MODE_PAD, EPI_KF, CH, 0><<<dim3(40, 1, BATCH), 512, 0, stream>>>(
      wkb, xpadT, kfT, bnS, bnT, 0, (long)NPAD * CH, (long)NSPAT * KCH, 40);
  // G3: v1T[b][n][vc] = relu(conv3x3(x))  (deep 256x128, asym ring)
  k_gemm2<MODE_CONV, EPI_V1, CH * 9, 1><<<dim3(80, 1, BATCH), 512, 0, stream>>>(
      wv1b, xpadT, v1T, bv1, nullptr, 0, (long)NPAD * CH, (long)NSPAT * VCH, 40);
  // G4: v[b][vc][n] = relu(wv2 . v1)
  k_gemm2<MODE_LIN, EPI_V, VCH, 1><<<dim3(80, 1, BATCH), 512, 0, stream>>>(
      wv2b, v1T, vB, bv2, nullptr, 0, (long)NSPAT * VCH, (long)VCH * NSPAT, 40);

  if (simb) {
    // G2: bf16 scores -> simb (transposed-symmetric write), 800 blocks/batch
    k_gemm2<MODE_LIN, EPI_SBF, KCH, 0><<<dim3(20 * 40, 1, BATCH), 512, 0, stream>>>(
        kfT, kfT, simb, nullptr, nullptr, (long)NSPAT * KCH, (long)NSPAT * KCH, (long)NSPAT * NSPAT, 40);
    k_softmax_bf<<<BATCH * NSPAT, 256, 0, stream>>>(simb, Sb);
    // G5 (swapped): ctx^T = sim . vB^T -- A=sim (4-way reuse, co-XCD), B=vB
    // (L2-hot); 16B ctx stores. Flattened grid 320, REMAP=2.
    k_gemm2<MODE_LIN, EPI_CTXT, NSPAT, 2><<<dim3(320, 1, 1), 512, 0, stream>>>(
        simb, vB, ctx, nullptr, nullptr, (long)NSPAT * NSPAT, (long)VCH * NSPAT, (long)VCH * NSPAT, 4);
  } else {
    // fallback: f32 scores -> d_out sim region, in-place softmax, f32-staged G5
    k_gemm<MODE_LIN, EPI_SF32, KCH, 40><<<dim3(40 * 40, 1, BATCH), 256, 0, stream>>>(
        kfT, kfT, Sb, nullptr, nullptr, (long)NSPAT * KCH, (long)NSPAT * KCH, (long)NSPAT * NSPAT);
    k_softmax<<<BATCH * NSPAT, 256, 0, stream>>>(Sb);
    k_gemm<MODE_SIMF32, EPI_CTX, NSPAT, 4><<<dim3(40 * 4, 1, BATCH), 256, 0, stream>>>(
        vB, Sb, ctx, nullptr, nullptr, (long)VCH * NSPAT, (long)NSPAT * NSPAT, (long)VCH * NSPAT);
  }
}